// Round 1
// baseline (2098.295 us; speedup 1.0000x reference)
//
#include <hip/hip_runtime.h>
#include <math.h>

#define N_NODES 100000
#define N_EDGES 1600000
#define UNITS   256
#define NGRAPH  512
#define IN_FEAT 9

// ============================ CSR build ============================

__global__ void k_count(const int* __restrict__ ei, int* __restrict__ cnt) {
  int e = blockIdx.x * blockDim.x + threadIdx.x;
  if (e < N_EDGES) atomicAdd(&cnt[ei[N_EDGES + e]], 1);
}

__global__ __launch_bounds__(1024) void k_scan(const int* __restrict__ cnt,
                                               int* __restrict__ row_ptr) {
  __shared__ int wsum[16];
  __shared__ int carryS;
  const int tid = threadIdx.x, lane = tid & 63, w = tid >> 6;
  if (tid == 0) carryS = 0;
  __syncthreads();
  for (int base = 0; base < N_NODES; base += 1024) {
    int idx = base + tid;
    int v = (idx < N_NODES) ? cnt[idx] : 0;
    int s = v;
    #pragma unroll
    for (int off = 1; off < 64; off <<= 1) {
      int t = __shfl_up(s, off);
      if (lane >= off) s += t;
    }
    if (lane == 63) wsum[w] = s;
    __syncthreads();
    if (w == 0 && lane < 16) {
      int ss = wsum[lane];
      #pragma unroll
      for (int off = 1; off < 16; off <<= 1) {
        int u = __shfl_up(ss, off);
        if (lane >= off) ss += u;
      }
      wsum[lane] = ss;   // inclusive wave-sum scan
    }
    __syncthreads();
    int waveoff = w ? wsum[w - 1] : 0;
    int carry = carryS;
    if (idx < N_NODES) row_ptr[idx] = carry + waveoff + s - v;  // exclusive
    __syncthreads();
    if (tid == 1023) carryS = carry + wsum[15];
    __syncthreads();
  }
  if (threadIdx.x == 0) row_ptr[N_NODES] = carryS;
}

__global__ void k_dinv(const int* __restrict__ cnt, float* __restrict__ dinv) {
  int n = blockIdx.x * blockDim.x + threadIdx.x;
  if (n < N_NODES) dinv[n] = rsqrtf((float)cnt[n] + 1.0f);  // +1 self-loop
}

__global__ void k_fill(const int* __restrict__ ei, const int* __restrict__ row_ptr,
                       int* __restrict__ fill, int* __restrict__ col) {
  int e = blockIdx.x * blockDim.x + threadIdx.x;
  if (e < N_EDGES) {
    int s = ei[e];
    int d = ei[N_EDGES + e];
    int pos = row_ptr[d] + atomicAdd(&fill[d], 1);
    col[pos] = s;
  }
}

// ============================ Aggregation ============================

// p0 = Ahat * x   (9 features, thread per node)
__global__ void k_agg9(const float* __restrict__ x, const int* __restrict__ row_ptr,
                       const int* __restrict__ col, const float* __restrict__ dinv,
                       float* __restrict__ p0) {
  int n = blockIdx.x * blockDim.x + threadIdx.x;
  if (n >= N_NODES) return;
  float dn = dinv[n];
  float acc[IN_FEAT];
  float selfw = dn * dn;
  #pragma unroll
  for (int j = 0; j < IN_FEAT; ++j) acc[j] = x[n * IN_FEAT + j] * selfw;
  int beg = row_ptr[n], end = row_ptr[n + 1];
  for (int e = beg; e < end; ++e) {
    int s = col[e];
    float wgt = dinv[s] * dn;
    #pragma unroll
    for (int j = 0; j < IN_FEAT; ++j) acc[j] += x[s * IN_FEAT + j] * wgt;
  }
  #pragma unroll
  for (int j = 0; j < IN_FEAT; ++j) p0[n * IN_FEAT + j] = acc[j];
}

// p = Ahat * h   (256 features, one wave per node, float4 per lane)
__global__ __launch_bounds__(256) void k_agg256(const float* __restrict__ h,
                                                const int* __restrict__ row_ptr,
                                                const int* __restrict__ col,
                                                const float* __restrict__ dinv,
                                                float* __restrict__ p) {
  int wid = threadIdx.x >> 6;
  int lane = threadIdx.x & 63;
  int n = blockIdx.x * 4 + wid;
  if (n >= N_NODES) return;
  float dn = dinv[n];
  float4 hv = *(const float4*)&h[(size_t)n * UNITS + lane * 4];
  float selfw = dn * dn;
  float4 acc;
  acc.x = hv.x * selfw; acc.y = hv.y * selfw; acc.z = hv.z * selfw; acc.w = hv.w * selfw;
  int beg = row_ptr[n], end = row_ptr[n + 1];
  for (int e = beg; e < end; ++e) {
    int s = col[e];
    float wgt = dinv[s] * dn;
    float4 v = *(const float4*)&h[(size_t)s * UNITS + lane * 4];
    acc.x += v.x * wgt; acc.y += v.y * wgt; acc.z += v.z * wgt; acc.w += v.w * wgt;
  }
  *(float4*)&p[(size_t)n * UNITS + lane * 4] = acc;
}

// ============================ GEMMs ============================

// h = tanh(p0 @ Win + bin)   [N,9] x [9,256]
__global__ __launch_bounds__(256) void k_gemm9(const float* __restrict__ p0,
                                               const float* __restrict__ Win,
                                               const float* __restrict__ bin,
                                               float* __restrict__ h) {
  __shared__ float pS[32][IN_FEAT];
  int tid = threadIdx.x;
  int row0 = blockIdx.x * 32;
  if (tid < 32 * IN_FEAT) {
    int r = tid / IN_FEAT;
    pS[r][tid % IN_FEAT] = (row0 + r < N_NODES) ? p0[row0 * IN_FEAT + tid] : 0.0f;
  }
  float wcol[IN_FEAT];
  #pragma unroll
  for (int k = 0; k < IN_FEAT; ++k) wcol[k] = Win[k * UNITS + tid];
  float b = bin[tid];
  __syncthreads();
  for (int r = 0; r < 32; ++r) {
    int gr = row0 + r;
    if (gr >= N_NODES) break;
    float a = b;
    #pragma unroll
    for (int k = 0; k < IN_FEAT; ++k) a += pS[r][k] * wcol[k];
    h[(size_t)gr * UNITS + tid] = tanhf(a);
  }
}

// C = act(A @ W + bias)   [M,256] x [256,256], 64x64x64 tiles, 4x4 per thread
#define GBM 64
#define GBN 64
#define GBK 64
__global__ __launch_bounds__(256) void k_gemm256(const float* __restrict__ A,
                                                 const float* __restrict__ W,
                                                 const float* __restrict__ bias,
                                                 float* __restrict__ C,
                                                 int M, int apply_tanh) {
  __shared__ float As[GBK][GBM + 4];  // transposed: As[k][m], stride 68 (16B-aligned rows)
  __shared__ float Bs[GBK][GBN + 4];
  const int tid = threadIdx.x;
  const int row0 = blockIdx.x * GBM;
  const int col0 = blockIdx.y * GBN;
  const int tx = tid & 15, ty = tid >> 4;
  const int lrow = tid >> 4;        // 0..15
  const int lc4 = (tid & 15) * 4;   // 0..60
  float acc[4][4] = {{0.f}};
  for (int k0 = 0; k0 < UNITS; k0 += GBK) {
    #pragma unroll
    for (int i = 0; i < 4; ++i) {   // A tile, store transposed
      int r = lrow + i * 16;
      int gr = row0 + r;
      float4 v = make_float4(0.f, 0.f, 0.f, 0.f);
      if (gr < M) v = *(const float4*)&A[(size_t)gr * UNITS + k0 + lc4];
      As[lc4 + 0][r] = v.x; As[lc4 + 1][r] = v.y;
      As[lc4 + 2][r] = v.z; As[lc4 + 3][r] = v.w;
    }
    #pragma unroll
    for (int i = 0; i < 4; ++i) {   // B tile
      int kk = lrow + i * 16;
      float4 v = *(const float4*)&W[(size_t)(k0 + kk) * UNITS + col0 + lc4];
      *(float4*)&Bs[kk][lc4] = v;
    }
    __syncthreads();
    #pragma unroll
    for (int k = 0; k < GBK; ++k) {
      float4 a = *(const float4*)&As[k][ty * 4];
      float4 b = *(const float4*)&Bs[k][tx * 4];
      acc[0][0] += a.x * b.x; acc[0][1] += a.x * b.y; acc[0][2] += a.x * b.z; acc[0][3] += a.x * b.w;
      acc[1][0] += a.y * b.x; acc[1][1] += a.y * b.y; acc[1][2] += a.y * b.z; acc[1][3] += a.y * b.w;
      acc[2][0] += a.z * b.x; acc[2][1] += a.z * b.y; acc[2][2] += a.z * b.z; acc[2][3] += a.z * b.w;
      acc[3][0] += a.w * b.x; acc[3][1] += a.w * b.y; acc[3][2] += a.w * b.z; acc[3][3] += a.w * b.w;
    }
    __syncthreads();
  }
  #pragma unroll
  for (int i = 0; i < 4; ++i) {
    int gr = row0 + ty * 4 + i;
    if (gr >= M) continue;
    #pragma unroll
    for (int j = 0; j < 4; ++j) {
      float v = acc[i][j] + bias[col0 + tx * 4 + j];
      if (apply_tanh) v = tanhf(v);
      C[(size_t)gr * UNITS + col0 + tx * 4 + j] = v;
    }
  }
}

// ============================ fc2 + fc3 + pool ============================

__global__ __launch_bounds__(256) void k_fc23_pool(const float* __restrict__ H,
                                                   const float* __restrict__ W2,
                                                   const float* __restrict__ b2,
                                                   const float* __restrict__ w3,
                                                   const float* __restrict__ b3,
                                                   const int* __restrict__ batch,
                                                   float* __restrict__ sums,
                                                   float* __restrict__ cnts) {
  __shared__ float w2S[UNITS * 32];   // 32 KiB
  __shared__ float rowS[8][UNITS];    // 8 KiB
  __shared__ float w3S[32];
  __shared__ float b2S[32];
  int tid = threadIdx.x;
  for (int i = tid; i < UNITS * 32; i += 256) w2S[i] = W2[i];
  if (tid < 32) { w3S[tid] = w3[tid]; b2S[tid] = b2[tid]; }
  __syncthreads();
  int g = tid >> 5;
  int c = tid & 31;
  int n = blockIdx.x * 8 + g;
  if (n >= N_NODES) return;
  #pragma unroll
  for (int j = 0; j < 8; ++j) rowS[g][c + j * 32] = H[(size_t)n * UNITS + c + j * 32];
  float acc = b2S[c];
  for (int k = 0; k < UNITS; ++k) acc += rowS[g][k] * w2S[k * 32 + c];
  float h2 = tanhf(acc);
  float part = h2 * w3S[c];
  #pragma unroll
  for (int m = 16; m >= 1; m >>= 1) part += __shfl_xor(part, m);
  if (c == 0) {
    float s = part + b3[0];
    int b = batch[n];
    atomicAdd(&sums[b], s);
    atomicAdd(&cnts[b], 1.0f);
  }
}

__global__ void k_final(const float* __restrict__ sums, const float* __restrict__ cnts,
                        float* __restrict__ out) {
  int gidx = blockIdx.x * blockDim.x + threadIdx.x;
  if (gidx < NGRAPH) {
    float m = sums[gidx] / fmaxf(cnts[gidx], 1.0f);
    out[gidx] = 1.0f / (1.0f + expf(-m));
  }
}

// ============================ launch ============================

extern "C" void kernel_launch(void* const* d_in, const int* in_sizes, int n_in,
                              void* d_out, int out_size, void* d_ws, size_t ws_size,
                              hipStream_t stream) {
  const float* x     = (const float*)d_in[0];
  const int*   ei    = (const int*)d_in[1];
  const int*   batch = (const int*)d_in[2];
  const float* Win   = (const float*)d_in[3];
  const float* bin_  = (const float*)d_in[4];
  const float* Ws    = (const float*)d_in[5];
  const float* bs    = (const float*)d_in[6];
  const float* fc1_w = (const float*)d_in[7];
  const float* fc1_b = (const float*)d_in[8];
  const float* fc2_w = (const float*)d_in[9];
  const float* fc2_b = (const float*)d_in[10];
  const float* fc3_w = (const float*)d_in[11];
  const float* fc3_b = (const float*)d_in[12];
  float* out = (float*)d_out;

  char* ws = (char*)d_ws;
  size_t off = 0;
  auto alloc = [&](size_t bytes) {
    size_t o = off;
    off = (off + bytes + 255) & ~(size_t)255;
    return o;
  };
  int*   cnt     = (int*)(ws + alloc(N_NODES * 4));
  int*   fill    = (int*)(ws + alloc(N_NODES * 4));
  int*   row_ptr = (int*)(ws + alloc((N_NODES + 1) * 4));
  float* dinv    = (float*)(ws + alloc(N_NODES * 4));
  int*   col     = (int*)(ws + alloc((size_t)N_EDGES * 4));
  float* sums    = (float*)(ws + alloc(NGRAPH * 4));
  float* cnts    = (float*)(ws + alloc(NGRAPH * 4));
  float* bufA    = (float*)(ws + alloc((size_t)N_NODES * UNITS * 4));
  float* bufB    = (float*)(ws + alloc((size_t)N_NODES * UNITS * 4));
  float* p0      = bufB;  // [N,9] lives in bufB before first GEMM

  // zero the counters / accumulators
  hipMemsetAsync(cnt, 0, N_NODES * 4, stream);
  hipMemsetAsync(fill, 0, N_NODES * 4, stream);
  hipMemsetAsync(sums, 0, NGRAPH * 4, stream);
  hipMemsetAsync(cnts, 0, NGRAPH * 4, stream);

  // CSR build
  k_count<<<(N_EDGES + 255) / 256, 256, 0, stream>>>(ei, cnt);
  k_scan<<<1, 1024, 0, stream>>>(cnt, row_ptr);
  k_dinv<<<(N_NODES + 255) / 256, 256, 0, stream>>>(cnt, dinv);
  k_fill<<<(N_EDGES + 255) / 256, 256, 0, stream>>>(ei, row_ptr, fill, col);

  // layer 0: aggregate 9 features, then GEMM 9->256 + tanh
  k_agg9<<<(N_NODES + 255) / 256, 256, 0, stream>>>(x, row_ptr, col, dinv, p0);
  k_gemm9<<<(N_NODES + 31) / 32, 256, 0, stream>>>(p0, Win, bin_, bufA);

  // layers 1..3: aggregate 256, GEMM 256x256 + tanh
  dim3 ggrid((N_NODES + GBM - 1) / GBM, UNITS / GBN);
  for (int i = 0; i < 3; ++i) {
    k_agg256<<<(N_NODES + 3) / 4, 256, 0, stream>>>(bufA, row_ptr, col, dinv, bufB);
    k_gemm256<<<ggrid, 256, 0, stream>>>(bufB, Ws + (size_t)i * UNITS * UNITS,
                                         bs + (size_t)i * UNITS, bufA, N_NODES, 1);
  }

  // fc1 + tanh
  k_gemm256<<<ggrid, 256, 0, stream>>>(bufA, fc1_w, fc1_b, bufB, N_NODES, 1);

  // fc2 + tanh + fc3 + mean-pool accumulate
  k_fc23_pool<<<(N_NODES + 7) / 8, 256, 0, stream>>>(bufB, fc2_w, fc2_b, fc3_w, fc3_b,
                                                     batch, sums, cnts);

  // sigmoid(mean)
  k_final<<<(NGRAPH + 255) / 256, 256, 0, stream>>>(sums, cnts, out);
}

// Round 2
// 1475.651 us; speedup vs baseline: 1.4219x; 1.4219x over previous
//
#include <hip/hip_runtime.h>
#include <math.h>

#define N_NODES 100000
#define N_EDGES 1600000
#define UNITS   256
#define NGRAPH  512
#define IN_FEAT 9

typedef short bf16x8 __attribute__((ext_vector_type(8)));
typedef float f32x4  __attribute__((ext_vector_type(4)));

__device__ __forceinline__ float bflo(unsigned int u) {
  return __builtin_bit_cast(float, u << 16);
}
__device__ __forceinline__ float bfhi(unsigned int u) {
  return __builtin_bit_cast(float, u & 0xffff0000u);
}
__device__ __forceinline__ unsigned short f2bf(float f) {
  unsigned int u = __builtin_bit_cast(unsigned int, f);
  u += 0x7fffu + ((u >> 16) & 1u);   // round-to-nearest-even
  return (unsigned short)(u >> 16);
}

// ============================ CSR build ============================

__global__ void k_count(const int* __restrict__ ei, int* __restrict__ cnt) {
  int e = blockIdx.x * blockDim.x + threadIdx.x;
  if (e < N_EDGES) atomicAdd(&cnt[ei[N_EDGES + e]], 1);
}

__global__ __launch_bounds__(1024) void k_scan(const int* __restrict__ cnt,
                                               int* __restrict__ row_ptr) {
  __shared__ int wsum[16];
  __shared__ int carryS;
  const int tid = threadIdx.x, lane = tid & 63, w = tid >> 6;
  if (tid == 0) carryS = 0;
  __syncthreads();
  for (int base = 0; base < N_NODES; base += 1024) {
    int idx = base + tid;
    int v = (idx < N_NODES) ? cnt[idx] : 0;
    int s = v;
    #pragma unroll
    for (int off = 1; off < 64; off <<= 1) {
      int t = __shfl_up(s, off);
      if (lane >= off) s += t;
    }
    if (lane == 63) wsum[w] = s;
    __syncthreads();
    if (w == 0 && lane < 16) {
      int ss = wsum[lane];
      #pragma unroll
      for (int off = 1; off < 16; off <<= 1) {
        int u = __shfl_up(ss, off);
        if (lane >= off) ss += u;
      }
      wsum[lane] = ss;   // inclusive wave-sum scan
    }
    __syncthreads();
    int waveoff = w ? wsum[w - 1] : 0;
    int carry = carryS;
    if (idx < N_NODES) row_ptr[idx] = carry + waveoff + s - v;  // exclusive
    __syncthreads();
    if (tid == 1023) carryS = carry + wsum[15];
    __syncthreads();
  }
  if (threadIdx.x == 0) row_ptr[N_NODES] = carryS;
}

__global__ void k_dinv(const int* __restrict__ cnt, float* __restrict__ dinv) {
  int n = blockIdx.x * blockDim.x + threadIdx.x;
  if (n < N_NODES) dinv[n] = rsqrtf((float)cnt[n] + 1.0f);  // +1 self-loop
}

__global__ void k_fill(const int* __restrict__ ei, const int* __restrict__ row_ptr,
                       int* __restrict__ fill, int* __restrict__ col) {
  int e = blockIdx.x * blockDim.x + threadIdx.x;
  if (e < N_EDGES) {
    int s = ei[e];
    int d = ei[N_EDGES + e];
    int pos = row_ptr[d] + atomicAdd(&fill[d], 1);
    col[pos] = s;
  }
}

// ============================ Weight transpose/convert ============================

// Wt[m][n][k] = W_m[k][n] as bf16; m = 0..2 -> Ws, m = 3 -> fc1_w
__global__ void k_cvtW(const float* __restrict__ Ws, const float* __restrict__ fc1_w,
                       unsigned short* __restrict__ Wt) {
  int idx = blockIdx.x * 256 + threadIdx.x;   // < 4*256*256
  int m = idx >> 16;
  int r = idx & 65535;
  int n = r >> 8;
  int k = r & 255;
  const float* src = (m < 3) ? (Ws + (size_t)m * 65536) : fc1_w;
  Wt[idx] = f2bf(src[k * 256 + n]);
}

// ============================ Aggregation ============================

// p0 = Ahat * x   (9 features, f32, thread per node)
__global__ void k_agg9(const float* __restrict__ x, const int* __restrict__ row_ptr,
                       const int* __restrict__ col, const float* __restrict__ dinv,
                       float* __restrict__ p0) {
  int n = blockIdx.x * blockDim.x + threadIdx.x;
  if (n >= N_NODES) return;
  float dn = dinv[n];
  float acc[IN_FEAT];
  float selfw = dn * dn;
  #pragma unroll
  for (int j = 0; j < IN_FEAT; ++j) acc[j] = x[n * IN_FEAT + j] * selfw;
  int beg = row_ptr[n], end = row_ptr[n + 1];
  for (int e = beg; e < end; ++e) {
    int s = col[e];
    float wgt = dinv[s] * dn;
    #pragma unroll
    for (int j = 0; j < IN_FEAT; ++j) acc[j] += x[s * IN_FEAT + j] * wgt;
  }
  #pragma unroll
  for (int j = 0; j < IN_FEAT; ++j) p0[n * IN_FEAT + j] = acc[j];
}

// p = Ahat * h   (256 bf16 features, one wave per node, 4 feats/lane, f32 acc)
__global__ __launch_bounds__(256) void k_agg256(
    const unsigned short* __restrict__ h, const int* __restrict__ row_ptr,
    const int* __restrict__ col, const float* __restrict__ dinv,
    unsigned short* __restrict__ p) {
  int wid = threadIdx.x >> 6;
  int lane = threadIdx.x & 63;
  int n = blockIdx.x * 4 + wid;
  if (n >= N_NODES) return;
  float dn = dinv[n];
  uint2 q = *(const uint2*)(h + (size_t)n * UNITS + lane * 4);
  float selfw = dn * dn;
  float a0 = bflo(q.x) * selfw, a1 = bfhi(q.x) * selfw;
  float a2 = bflo(q.y) * selfw, a3 = bfhi(q.y) * selfw;
  int e = row_ptr[n], end = row_ptr[n + 1];
  for (; e + 2 <= end; e += 2) {          // 2-edge unroll: 2 gathers in flight
    int s0 = col[e], s1 = col[e + 1];
    float w0 = dinv[s0] * dn, w1 = dinv[s1] * dn;
    uint2 q0 = *(const uint2*)(h + (size_t)s0 * UNITS + lane * 4);
    uint2 q1 = *(const uint2*)(h + (size_t)s1 * UNITS + lane * 4);
    a0 += bflo(q0.x) * w0; a1 += bfhi(q0.x) * w0;
    a2 += bflo(q0.y) * w0; a3 += bfhi(q0.y) * w0;
    a0 += bflo(q1.x) * w1; a1 += bfhi(q1.x) * w1;
    a2 += bflo(q1.y) * w1; a3 += bfhi(q1.y) * w1;
  }
  if (e < end) {
    int s0 = col[e];
    float w0 = dinv[s0] * dn;
    uint2 q0 = *(const uint2*)(h + (size_t)s0 * UNITS + lane * 4);
    a0 += bflo(q0.x) * w0; a1 += bfhi(q0.x) * w0;
    a2 += bflo(q0.y) * w0; a3 += bfhi(q0.y) * w0;
  }
  uint2 o;
  o.x = (unsigned int)f2bf(a0) | ((unsigned int)f2bf(a1) << 16);
  o.y = (unsigned int)f2bf(a2) | ((unsigned int)f2bf(a3) << 16);
  *(uint2*)(p + (size_t)n * UNITS + lane * 4) = o;
}

// ============================ GEMMs ============================

// h = tanh(p0 @ Win + bin) -> bf16   [N,9] x [9,256]
__global__ __launch_bounds__(256) void k_gemm9(const float* __restrict__ p0,
                                               const float* __restrict__ Win,
                                               const float* __restrict__ bin,
                                               unsigned short* __restrict__ h) {
  __shared__ float pS[32][IN_FEAT];
  int tid = threadIdx.x;
  int row0 = blockIdx.x * 32;
  for (int i = tid; i < 32 * IN_FEAT; i += 256) {   // full 288-entry fill (bug fix)
    int r = i / IN_FEAT;
    pS[r][i % IN_FEAT] = (row0 + r < N_NODES) ? p0[(size_t)row0 * IN_FEAT + i] : 0.0f;
  }
  float wcol[IN_FEAT];
  #pragma unroll
  for (int k = 0; k < IN_FEAT; ++k) wcol[k] = Win[k * UNITS + tid];
  float b = bin[tid];
  __syncthreads();
  for (int r = 0; r < 32; ++r) {
    int gr = row0 + r;
    if (gr >= N_NODES) break;
    float a = b;
    #pragma unroll
    for (int k = 0; k < IN_FEAT; ++k) a += pS[r][k] * wcol[k];
    h[(size_t)gr * UNITS + tid] = f2bf(tanhf(a));
  }
}

// C = tanh(A @ W + bias) in bf16. A:[M][256] bf16, Wt:[256][256] bf16 (Wt[n][k]).
// 4 waves/block; wave w owns rows [row0+16w, +16) x all 256 cols.
// MFMA 16x16x32; A and B fragments use the IDENTICAL (blk,elem)->k index
// function, so any HW k-permutation cancels in the dot product.
__global__ __launch_bounds__(256) void k_gemm_bf16(
    const unsigned short* __restrict__ A,
    const unsigned short* __restrict__ Wt,
    const float* __restrict__ bias,
    unsigned short* __restrict__ C,
    int M) {
  __shared__ unsigned short tS[64][264];   // 33.8 KiB, rows 528B (16B-aligned)
  const int tid = threadIdx.x;
  const int w = tid >> 6;
  const int l = tid & 63;
  const int l15 = l & 15;
  const int blk = l >> 4;
  const int row0 = blockIdx.x * 64;

  int r = row0 + 16 * w + l15;
  int rc = r < M ? r : M - 1;              // clamp loads; stores guarded below
  const unsigned short* aPtr = A + (size_t)rc * UNITS + 8 * blk;
  const unsigned short* bPtr = Wt + (size_t)l15 * UNITS + 8 * blk;

  f32x4 acc[16];
  #pragma unroll
  for (int cf = 0; cf < 16; ++cf) acc[cf] = (f32x4){0.f, 0.f, 0.f, 0.f};

  for (int k0 = 0; k0 < UNITS; k0 += 32) {
    bf16x8 a = *(const bf16x8*)(aPtr + k0);
    const unsigned short* bp = bPtr + k0;
    #pragma unroll
    for (int cf = 0; cf < 16; ++cf) {
      bf16x8 b = *(const bf16x8*)bp;
      acc[cf] = __builtin_amdgcn_mfma_f32_16x16x32_bf16(a, b, acc[cf], 0, 0, 0);
      bp += 16 * UNITS;
    }
  }

  // bias + tanh -> bf16 into LDS (C/D frag: col=lane&15, row=4*(lane>>4)+reg)
  #pragma unroll
  for (int cf = 0; cf < 16; ++cf) {
    float bcol = bias[cf * 16 + l15];
    #pragma unroll
    for (int reg = 0; reg < 4; ++reg) {
      float v = tanhf(acc[cf][reg] + bcol);
      tS[16 * w + 4 * blk + reg][cf * 16 + l15] = f2bf(v);
    }
  }
  __syncthreads();
  #pragma unroll
  for (int i = 0; i < 4; ++i) {            // coalesced 16B stores
    int flat8 = tid + i * 256;             // ushort8 index in 64x256 tile
    int rr = flat8 >> 5;
    int c8 = flat8 & 31;
    int gr = row0 + rr;
    if (gr < M) {
      uint4 v = *(const uint4*)&tS[rr][c8 * 8];
      *(uint4*)(C + (size_t)gr * UNITS + c8 * 8) = v;
    }
  }
}

// ============================ fc2 + fc3 + pool ============================

__global__ __launch_bounds__(256) void k_fc23_pool(
    const unsigned short* __restrict__ H,
    const float* __restrict__ W2, const float* __restrict__ b2,
    const float* __restrict__ w3, const float* __restrict__ b3,
    const int* __restrict__ batch,
    float* __restrict__ sums, float* __restrict__ cnts) {
  __shared__ float w2S[UNITS * 32];
  __shared__ float rowS[8][UNITS];
  __shared__ float w3S[32];
  __shared__ float b2S[32];
  int tid = threadIdx.x;
  for (int i = tid; i < UNITS * 32; i += 256) w2S[i] = W2[i];
  if (tid < 32) { w3S[tid] = w3[tid]; b2S[tid] = b2[tid]; }
  __syncthreads();
  int g = tid >> 5;
  int c = tid & 31;
  int n = blockIdx.x * 8 + g;
  if (n >= N_NODES) return;
  #pragma unroll
  for (int j = 0; j < 8; ++j)
    rowS[g][c + j * 32] = bflo((unsigned int)H[(size_t)n * UNITS + c + j * 32]);
  float acc = b2S[c];
  for (int k = 0; k < UNITS; ++k) acc += rowS[g][k] * w2S[k * 32 + c];
  float h2 = tanhf(acc);
  float part = h2 * w3S[c];
  #pragma unroll
  for (int m = 16; m >= 1; m >>= 1) part += __shfl_xor(part, m);
  if (c == 0) {
    float s = part + b3[0];
    int b = batch[n];
    atomicAdd(&sums[b], s);
    atomicAdd(&cnts[b], 1.0f);
  }
}

__global__ void k_final(const float* __restrict__ sums, const float* __restrict__ cnts,
                        float* __restrict__ out) {
  int gidx = blockIdx.x * blockDim.x + threadIdx.x;
  if (gidx < NGRAPH) {
    float m = sums[gidx] / fmaxf(cnts[gidx], 1.0f);
    out[gidx] = 1.0f / (1.0f + expf(-m));
  }
}

// ============================ launch ============================

extern "C" void kernel_launch(void* const* d_in, const int* in_sizes, int n_in,
                              void* d_out, int out_size, void* d_ws, size_t ws_size,
                              hipStream_t stream) {
  const float* x     = (const float*)d_in[0];
  const int*   ei    = (const int*)d_in[1];
  const int*   batch = (const int*)d_in[2];
  const float* Win   = (const float*)d_in[3];
  const float* bin_  = (const float*)d_in[4];
  const float* Ws    = (const float*)d_in[5];
  const float* bs    = (const float*)d_in[6];
  const float* fc1_w = (const float*)d_in[7];
  const float* fc1_b = (const float*)d_in[8];
  const float* fc2_w = (const float*)d_in[9];
  const float* fc2_b = (const float*)d_in[10];
  const float* fc3_w = (const float*)d_in[11];
  const float* fc3_b = (const float*)d_in[12];
  float* out = (float*)d_out;

  char* ws = (char*)d_ws;
  size_t off = 0;
  auto alloc = [&](size_t bytes) {
    size_t o = off;
    off = (off + bytes + 255) & ~(size_t)255;
    return o;
  };
  int*   cnt     = (int*)(ws + alloc(N_NODES * 4));
  int*   fill    = (int*)(ws + alloc(N_NODES * 4));
  int*   row_ptr = (int*)(ws + alloc((N_NODES + 1) * 4));
  float* dinv    = (float*)(ws + alloc(N_NODES * 4));
  int*   col     = (int*)(ws + alloc((size_t)N_EDGES * 4));
  float* sums    = (float*)(ws + alloc(NGRAPH * 4));
  float* cnts    = (float*)(ws + alloc(NGRAPH * 4));
  float* p0      = (float*)(ws + alloc((size_t)N_NODES * IN_FEAT * 4));
  unsigned short* Wt   = (unsigned short*)(ws + alloc((size_t)4 * UNITS * UNITS * 2));
  unsigned short* bufA = (unsigned short*)(ws + alloc((size_t)N_NODES * UNITS * 2));
  unsigned short* bufB = (unsigned short*)(ws + alloc((size_t)N_NODES * UNITS * 2));

  hipMemsetAsync(cnt, 0, N_NODES * 4, stream);
  hipMemsetAsync(fill, 0, N_NODES * 4, stream);
  hipMemsetAsync(sums, 0, NGRAPH * 4, stream);
  hipMemsetAsync(cnts, 0, NGRAPH * 4, stream);

  // weights -> bf16 transposed (Wt[m][n][k])
  k_cvtW<<<(4 * UNITS * UNITS) / 256, 256, 0, stream>>>(Ws, fc1_w, Wt);

  // CSR build
  k_count<<<(N_EDGES + 255) / 256, 256, 0, stream>>>(ei, cnt);
  k_scan<<<1, 1024, 0, stream>>>(cnt, row_ptr);
  k_dinv<<<(N_NODES + 255) / 256, 256, 0, stream>>>(cnt, dinv);
  k_fill<<<(N_EDGES + 255) / 256, 256, 0, stream>>>(ei, row_ptr, fill, col);

  // layer 0: aggregate 9 f32 feats, GEMM 9->256 + tanh -> bf16
  k_agg9<<<(N_NODES + 255) / 256, 256, 0, stream>>>(x, row_ptr, col, dinv, p0);
  k_gemm9<<<(N_NODES + 31) / 32, 256, 0, stream>>>(p0, Win, bin_, bufA);

  // layers 1..3: bf16 aggregate, MFMA GEMM + tanh
  int ggrid = (N_NODES + 63) / 64;
  for (int i = 0; i < 3; ++i) {
    k_agg256<<<(N_NODES + 3) / 4, 256, 0, stream>>>(bufA, row_ptr, col, dinv, bufB);
    k_gemm_bf16<<<ggrid, 256, 0, stream>>>(bufB, Wt + (size_t)i * UNITS * UNITS,
                                           bs + (size_t)i * UNITS, bufA, N_NODES);
  }

  // fc1 + tanh
  k_gemm_bf16<<<ggrid, 256, 0, stream>>>(bufA, Wt + (size_t)3 * UNITS * UNITS,
                                         fc1_b, bufB, N_NODES);

  // fc2 + tanh + fc3 + mean-pool accumulate
  k_fc23_pool<<<(N_NODES + 7) / 8, 256, 0, stream>>>(bufB, fc2_w, fc2_b, fc3_w, fc3_b,
                                                     batch, sums, cnts);

  // sigmoid(mean)
  k_final<<<(NGRAPH + 255) / 256, 256, 0, stream>>>(sums, cnts, out);
}

// Round 3
// 1352.861 us; speedup vs baseline: 1.5510x; 1.0908x over previous
//
#include <hip/hip_runtime.h>
#include <math.h>

#define N_NODES 100000
#define N_EDGES 1600000
#define UNITS   256
#define NGRAPH  512
#define IN_FEAT 9

typedef short bf16x8 __attribute__((ext_vector_type(8)));
typedef float f32x4  __attribute__((ext_vector_type(4)));

__device__ __forceinline__ float bflo(unsigned int u) {
  return __builtin_bit_cast(float, u << 16);
}
__device__ __forceinline__ float bfhi(unsigned int u) {
  return __builtin_bit_cast(float, u & 0xffff0000u);
}
__device__ __forceinline__ unsigned short f2bf(float f) {
  unsigned int u = __builtin_bit_cast(unsigned int, f);
  u += 0x7fffu + ((u >> 16) & 1u);   // round-to-nearest-even
  return (unsigned short)(u >> 16);
}

// ============================ CSR build ============================

__global__ void k_count(const int* __restrict__ ei, int* __restrict__ cnt) {
  int e = blockIdx.x * blockDim.x + threadIdx.x;
  if (e < N_EDGES) atomicAdd(&cnt[ei[N_EDGES + e]], 1);
}

__global__ __launch_bounds__(1024) void k_scan(const int* __restrict__ cnt,
                                               int* __restrict__ row_ptr) {
  __shared__ int wsum[16];
  __shared__ int carryS;
  const int tid = threadIdx.x, lane = tid & 63, w = tid >> 6;
  if (tid == 0) carryS = 0;
  __syncthreads();
  for (int base = 0; base < N_NODES; base += 1024) {
    int idx = base + tid;
    int v = (idx < N_NODES) ? cnt[idx] : 0;
    int s = v;
    #pragma unroll
    for (int off = 1; off < 64; off <<= 1) {
      int t = __shfl_up(s, off);
      if (lane >= off) s += t;
    }
    if (lane == 63) wsum[w] = s;
    __syncthreads();
    if (w == 0 && lane < 16) {
      int ss = wsum[lane];
      #pragma unroll
      for (int off = 1; off < 16; off <<= 1) {
        int u = __shfl_up(ss, off);
        if (lane >= off) ss += u;
      }
      wsum[lane] = ss;   // inclusive wave-sum scan
    }
    __syncthreads();
    int waveoff = w ? wsum[w - 1] : 0;
    int carry = carryS;
    if (idx < N_NODES) row_ptr[idx] = carry + waveoff + s - v;  // exclusive
    __syncthreads();
    if (tid == 1023) carryS = carry + wsum[15];
    __syncthreads();
  }
  if (threadIdx.x == 0) row_ptr[N_NODES] = carryS;
}

__global__ void k_dinv(const int* __restrict__ cnt, float* __restrict__ dinv) {
  int n = blockIdx.x * blockDim.x + threadIdx.x;
  if (n < N_NODES) dinv[n] = rsqrtf((float)cnt[n] + 1.0f);  // +1 self-loop
}

__global__ void k_fill(const int* __restrict__ ei, const int* __restrict__ row_ptr,
                       int* __restrict__ fill, int* __restrict__ col) {
  int e = blockIdx.x * blockDim.x + threadIdx.x;
  if (e < N_EDGES) {
    int s = ei[e];
    int d = ei[N_EDGES + e];
    int pos = row_ptr[d] + atomicAdd(&fill[d], 1);
    col[pos] = s;
  }
}

// per-graph node counts via binary search on sorted batch (no atomics)
__global__ void k_cnts(const int* __restrict__ batch, float* __restrict__ cnts) {
  int g = blockIdx.x * blockDim.x + threadIdx.x;
  if (g >= NGRAPH) return;
  int lo = 0, hi = N_NODES;
  while (lo < hi) { int m = (lo + hi) >> 1; if (batch[m] < g) lo = m + 1; else hi = m; }
  int start = lo;
  lo = start; hi = N_NODES;
  while (lo < hi) { int m = (lo + hi) >> 1; if (batch[m] < g + 1) lo = m + 1; else hi = m; }
  cnts[g] = (float)(lo - start);
}

// ============================ Weight transpose/convert ============================

// Wt[m][n][k] = W_m[k][n] as bf16; m = 0..2 -> Ws, m = 3 -> fc1_w
__global__ void k_cvtW(const float* __restrict__ Ws, const float* __restrict__ fc1_w,
                       unsigned short* __restrict__ Wt) {
  int idx = blockIdx.x * 256 + threadIdx.x;   // < 4*256*256
  int m = idx >> 16;
  int r = idx & 65535;
  int n = r >> 8;
  int k = r & 255;
  const float* src = (m < 3) ? (Ws + (size_t)m * 65536) : fc1_w;
  Wt[idx] = f2bf(src[k * 256 + n]);
}

// Wt2[n][k] = fc2_w[k][n] as bf16 (32x256)
__global__ void k_cvtW2(const float* __restrict__ fc2_w, unsigned short* __restrict__ Wt2) {
  int idx = blockIdx.x * 256 + threadIdx.x;   // < 32*256
  int n = idx >> 8;
  int k = idx & 255;
  Wt2[idx] = f2bf(fc2_w[k * 32 + n]);
}

// ============================ Aggregation ============================

// p0 = Ahat * x   (9 features, f32, thread per node)
__global__ void k_agg9(const float* __restrict__ x, const int* __restrict__ row_ptr,
                       const int* __restrict__ col, const float* __restrict__ dinv,
                       float* __restrict__ p0) {
  int n = blockIdx.x * blockDim.x + threadIdx.x;
  if (n >= N_NODES) return;
  float dn = dinv[n];
  float acc[IN_FEAT];
  float selfw = dn * dn;
  #pragma unroll
  for (int j = 0; j < IN_FEAT; ++j) acc[j] = x[n * IN_FEAT + j] * selfw;
  int beg = row_ptr[n], end = row_ptr[n + 1];
  for (int e = beg; e < end; ++e) {
    int s = col[e];
    float wgt = dinv[s] * dn;
    #pragma unroll
    for (int j = 0; j < IN_FEAT; ++j) acc[j] += x[s * IN_FEAT + j] * wgt;
  }
  #pragma unroll
  for (int j = 0; j < IN_FEAT; ++j) p0[n * IN_FEAT + j] = acc[j];
}

// p = Ahat * h   (256 bf16 features, one wave per node, 4 feats/lane, f32 acc)
__global__ __launch_bounds__(256) void k_agg256(
    const unsigned short* __restrict__ h, const int* __restrict__ row_ptr,
    const int* __restrict__ col, const float* __restrict__ dinv,
    unsigned short* __restrict__ p) {
  int wid = threadIdx.x >> 6;
  int lane = threadIdx.x & 63;
  int n = blockIdx.x * 4 + wid;
  if (n >= N_NODES) return;
  float dn = dinv[n];
  uint2 q = *(const uint2*)(h + (size_t)n * UNITS + lane * 4);
  float selfw = dn * dn;
  float a0 = bflo(q.x) * selfw, a1 = bfhi(q.x) * selfw;
  float a2 = bflo(q.y) * selfw, a3 = bfhi(q.y) * selfw;
  int e = row_ptr[n], end = row_ptr[n + 1];
  for (; e + 2 <= end; e += 2) {          // 2-edge unroll: 2 gathers in flight
    int s0 = col[e], s1 = col[e + 1];
    float w0 = dinv[s0] * dn, w1 = dinv[s1] * dn;
    uint2 q0 = *(const uint2*)(h + (size_t)s0 * UNITS + lane * 4);
    uint2 q1 = *(const uint2*)(h + (size_t)s1 * UNITS + lane * 4);
    a0 += bflo(q0.x) * w0; a1 += bfhi(q0.x) * w0;
    a2 += bflo(q0.y) * w0; a3 += bfhi(q0.y) * w0;
    a0 += bflo(q1.x) * w1; a1 += bfhi(q1.x) * w1;
    a2 += bflo(q1.y) * w1; a3 += bfhi(q1.y) * w1;
  }
  if (e < end) {
    int s0 = col[e];
    float w0 = dinv[s0] * dn;
    uint2 q0 = *(const uint2*)(h + (size_t)s0 * UNITS + lane * 4);
    a0 += bflo(q0.x) * w0; a1 += bfhi(q0.x) * w0;
    a2 += bflo(q0.y) * w0; a3 += bfhi(q0.y) * w0;
  }
  uint2 o;
  o.x = (unsigned int)f2bf(a0) | ((unsigned int)f2bf(a1) << 16);
  o.y = (unsigned int)f2bf(a2) | ((unsigned int)f2bf(a3) << 16);
  *(uint2*)(p + (size_t)n * UNITS + lane * 4) = o;
}

// ============================ GEMMs ============================

// h = tanh(p0 @ Win + bin) -> bf16   [N,9] x [9,256]
__global__ __launch_bounds__(256) void k_gemm9(const float* __restrict__ p0,
                                               const float* __restrict__ Win,
                                               const float* __restrict__ bin,
                                               unsigned short* __restrict__ h) {
  __shared__ float pS[32][IN_FEAT];
  int tid = threadIdx.x;
  int row0 = blockIdx.x * 32;
  for (int i = tid; i < 32 * IN_FEAT; i += 256) {
    int r = i / IN_FEAT;
    pS[r][i % IN_FEAT] = (row0 + r < N_NODES) ? p0[(size_t)row0 * IN_FEAT + i] : 0.0f;
  }
  float wcol[IN_FEAT];
  #pragma unroll
  for (int k = 0; k < IN_FEAT; ++k) wcol[k] = Win[k * UNITS + tid];
  float b = bin[tid];
  __syncthreads();
  for (int r = 0; r < 32; ++r) {
    int gr = row0 + r;
    if (gr >= N_NODES) break;
    float a = b;
    #pragma unroll
    for (int k = 0; k < IN_FEAT; ++k) a += pS[r][k] * wcol[k];
    h[(size_t)gr * UNITS + tid] = f2bf(tanhf(a));
  }
}

// C = tanh(A @ W + bias) in bf16. A:[M][256] bf16, Wt:[256][256] bf16 (Wt[n][k]).
// 4 waves/block; wave w owns rows [row0+16w, +16) x all 256 cols.
__global__ __launch_bounds__(256) void k_gemm_bf16(
    const unsigned short* __restrict__ A,
    const unsigned short* __restrict__ Wt,
    const float* __restrict__ bias,
    unsigned short* __restrict__ C,
    int M) {
  __shared__ unsigned short tS[64][264];   // 33.8 KiB, rows 528B (16B-aligned)
  const int tid = threadIdx.x;
  const int w = tid >> 6;
  const int l = tid & 63;
  const int l15 = l & 15;
  const int blk = l >> 4;
  const int row0 = blockIdx.x * 64;

  int r = row0 + 16 * w + l15;
  int rc = r < M ? r : M - 1;              // clamp loads; stores guarded below
  const unsigned short* aPtr = A + (size_t)rc * UNITS + 8 * blk;
  const unsigned short* bPtr = Wt + (size_t)l15 * UNITS + 8 * blk;

  f32x4 acc[16];
  #pragma unroll
  for (int cf = 0; cf < 16; ++cf) acc[cf] = (f32x4){0.f, 0.f, 0.f, 0.f};

  for (int k0 = 0; k0 < UNITS; k0 += 32) {
    bf16x8 a = *(const bf16x8*)(aPtr + k0);
    const unsigned short* bp = bPtr + k0;
    #pragma unroll
    for (int cf = 0; cf < 16; ++cf) {
      bf16x8 b = *(const bf16x8*)bp;
      acc[cf] = __builtin_amdgcn_mfma_f32_16x16x32_bf16(a, b, acc[cf], 0, 0, 0);
      bp += 16 * UNITS;
    }
  }

  // bias + tanh -> bf16 into LDS (C/D frag: col=lane&15, row=4*(lane>>4)+reg)
  #pragma unroll
  for (int cf = 0; cf < 16; ++cf) {
    float bcol = bias[cf * 16 + l15];
    #pragma unroll
    for (int reg = 0; reg < 4; ++reg) {
      float v = tanhf(acc[cf][reg] + bcol);
      tS[16 * w + 4 * blk + reg][cf * 16 + l15] = f2bf(v);
    }
  }
  __syncthreads();
  #pragma unroll
  for (int i = 0; i < 4; ++i) {            // coalesced 16B stores
    int flat8 = tid + i * 256;             // ushort8 index in 64x256 tile
    int rr = flat8 >> 5;
    int c8 = flat8 & 31;
    int gr = row0 + rr;
    if (gr < M) {
      uint4 v = *(const uint4*)&tS[rr][c8 * 8];
      *(uint4*)(C + (size_t)gr * UNITS + c8 * 8) = v;
    }
  }
}

// ============================ fused fc2 + tanh + fc3 + pool (MFMA) ============================

// H:[M][256] bf16, Wt2:[32][256] bf16. Per wave: 16 rows x 32 cols (2 frags).
// Epilogue: tanh(acc+b2)*w3, shfl row-reduce over 16-lane col group,
// one atomicAdd per node row into sums[batch[row]].
__global__ __launch_bounds__(256) void k_fc23p(
    const unsigned short* __restrict__ H,
    const unsigned short* __restrict__ Wt2,
    const float* __restrict__ b2,
    const float* __restrict__ w3, const float* __restrict__ b3,
    const int* __restrict__ batch,
    float* __restrict__ sums, int M) {
  const int tid = threadIdx.x;
  const int w = tid >> 6;
  const int l = tid & 63;
  const int l15 = l & 15;
  const int blk = l >> 4;
  const int row0 = blockIdx.x * 64 + 16 * w;

  int r = row0 + l15;
  int rc = r < M ? r : M - 1;
  const unsigned short* aPtr = H + (size_t)rc * UNITS + 8 * blk;
  const unsigned short* bPtr = Wt2 + (size_t)l15 * UNITS + 8 * blk;

  f32x4 acc0 = (f32x4){0.f, 0.f, 0.f, 0.f};
  f32x4 acc1 = (f32x4){0.f, 0.f, 0.f, 0.f};
  #pragma unroll
  for (int k0 = 0; k0 < UNITS; k0 += 32) {
    bf16x8 a  = *(const bf16x8*)(aPtr + k0);
    bf16x8 b0 = *(const bf16x8*)(bPtr + k0);
    bf16x8 b1 = *(const bf16x8*)(bPtr + 16 * UNITS + k0);
    acc0 = __builtin_amdgcn_mfma_f32_16x16x32_bf16(a, b0, acc0, 0, 0, 0);
    acc1 = __builtin_amdgcn_mfma_f32_16x16x32_bf16(a, b1, acc1, 0, 0, 0);
  }

  float c0 = b2[l15], c1 = b2[16 + l15];
  float w30 = w3[l15], w31 = w3[16 + l15];
  float b3v = b3[0];
  #pragma unroll
  for (int reg = 0; reg < 4; ++reg) {
    float part = tanhf(acc0[reg] + c0) * w30 + tanhf(acc1[reg] + c1) * w31;
    #pragma unroll
    for (int m = 8; m >= 1; m >>= 1) part += __shfl_xor(part, m);
    int gr = row0 + 4 * blk + reg;
    if (l15 == 0 && gr < M) atomicAdd(&sums[batch[gr]], part + b3v);
  }
}

__global__ void k_final(const float* __restrict__ sums, const float* __restrict__ cnts,
                        float* __restrict__ out) {
  int gidx = blockIdx.x * blockDim.x + threadIdx.x;
  if (gidx < NGRAPH) {
    float m = sums[gidx] / fmaxf(cnts[gidx], 1.0f);
    out[gidx] = 1.0f / (1.0f + expf(-m));
  }
}

// ============================ launch ============================

extern "C" void kernel_launch(void* const* d_in, const int* in_sizes, int n_in,
                              void* d_out, int out_size, void* d_ws, size_t ws_size,
                              hipStream_t stream) {
  const float* x     = (const float*)d_in[0];
  const int*   ei    = (const int*)d_in[1];
  const int*   batch = (const int*)d_in[2];
  const float* Win   = (const float*)d_in[3];
  const float* bin_  = (const float*)d_in[4];
  const float* Ws    = (const float*)d_in[5];
  const float* bs    = (const float*)d_in[6];
  const float* fc1_w = (const float*)d_in[7];
  const float* fc1_b = (const float*)d_in[8];
  const float* fc2_w = (const float*)d_in[9];
  const float* fc2_b = (const float*)d_in[10];
  const float* fc3_w = (const float*)d_in[11];
  const float* fc3_b = (const float*)d_in[12];
  float* out = (float*)d_out;

  char* ws = (char*)d_ws;
  size_t off = 0;
  auto alloc = [&](size_t bytes) {
    size_t o = off;
    off = (off + bytes + 255) & ~(size_t)255;
    return o;
  };
  int*   cnt     = (int*)(ws + alloc(N_NODES * 4));
  int*   fill    = (int*)(ws + alloc(N_NODES * 4));
  int*   row_ptr = (int*)(ws + alloc((N_NODES + 1) * 4));
  float* dinv    = (float*)(ws + alloc(N_NODES * 4));
  int*   col     = (int*)(ws + alloc((size_t)N_EDGES * 4));
  float* sums    = (float*)(ws + alloc(NGRAPH * 4));
  float* cnts    = (float*)(ws + alloc(NGRAPH * 4));
  float* p0      = (float*)(ws + alloc((size_t)N_NODES * IN_FEAT * 4));
  unsigned short* Wt   = (unsigned short*)(ws + alloc((size_t)4 * UNITS * UNITS * 2));
  unsigned short* Wt2  = (unsigned short*)(ws + alloc((size_t)32 * UNITS * 2));
  unsigned short* bufA = (unsigned short*)(ws + alloc((size_t)N_NODES * UNITS * 2));
  unsigned short* bufB = (unsigned short*)(ws + alloc((size_t)N_NODES * UNITS * 2));

  hipMemsetAsync(cnt, 0, N_NODES * 4, stream);
  hipMemsetAsync(fill, 0, N_NODES * 4, stream);
  hipMemsetAsync(sums, 0, NGRAPH * 4, stream);

  // weights -> bf16 transposed
  k_cvtW<<<(4 * UNITS * UNITS) / 256, 256, 0, stream>>>(Ws, fc1_w, Wt);
  k_cvtW2<<<32, 256, 0, stream>>>(fc2_w, Wt2);

  // CSR build + per-graph counts
  k_count<<<(N_EDGES + 255) / 256, 256, 0, stream>>>(ei, cnt);
  k_scan<<<1, 1024, 0, stream>>>(cnt, row_ptr);
  k_dinv<<<(N_NODES + 255) / 256, 256, 0, stream>>>(cnt, dinv);
  k_fill<<<(N_EDGES + 255) / 256, 256, 0, stream>>>(ei, row_ptr, fill, col);
  k_cnts<<<2, 256, 0, stream>>>(batch, cnts);

  // layer 0: aggregate 9 f32 feats, GEMM 9->256 + tanh -> bf16
  k_agg9<<<(N_NODES + 255) / 256, 256, 0, stream>>>(x, row_ptr, col, dinv, p0);
  k_gemm9<<<(N_NODES + 31) / 32, 256, 0, stream>>>(p0, Win, bin_, bufA);

  // layers 1..3: bf16 aggregate, MFMA GEMM + tanh
  int ggrid = (N_NODES + 63) / 64;
  for (int i = 0; i < 3; ++i) {
    k_agg256<<<(N_NODES + 3) / 4, 256, 0, stream>>>(bufA, row_ptr, col, dinv, bufB);
    k_gemm_bf16<<<ggrid, 256, 0, stream>>>(bufB, Wt + (size_t)i * UNITS * UNITS,
                                           bs + (size_t)i * UNITS, bufA, N_NODES);
  }

  // fc1 + tanh
  k_gemm_bf16<<<ggrid, 256, 0, stream>>>(bufA, Wt + (size_t)3 * UNITS * UNITS,
                                         fc1_b, bufB, N_NODES);

  // fused fc2 + tanh + fc3 + mean-pool accumulate (MFMA)
  k_fc23p<<<ggrid, 256, 0, stream>>>(bufB, Wt2, fc2_b, fc3_w, fc3_b, batch, sums, N_NODES);

  // sigmoid(mean)
  k_final<<<(NGRAPH + 255) / 256, 256, 0, stream>>>(sums, cnts, out);
}

// Round 4
// 1214.221 us; speedup vs baseline: 1.7281x; 1.1142x over previous
//
#include <hip/hip_runtime.h>
#include <math.h>

#define N_NODES 100000
#define N_EDGES 1600000
#define UNITS   256
#define NGRAPH  512
#define IN_FEAT 9

typedef short bf16x8 __attribute__((ext_vector_type(8)));
typedef float f32x4  __attribute__((ext_vector_type(4)));

__device__ __forceinline__ float bflo(unsigned int u) {
  return __builtin_bit_cast(float, u << 16);
}
__device__ __forceinline__ float bfhi(unsigned int u) {
  return __builtin_bit_cast(float, u & 0xffff0000u);
}
__device__ __forceinline__ unsigned short f2bf(float f) {
  unsigned int u = __builtin_bit_cast(unsigned int, f);
  u += 0x7fffu + ((u >> 16) & 1u);   // round-to-nearest-even
  return (unsigned short)(u >> 16);
}

// ============================ CSR build ============================

__global__ void k_count(const int* __restrict__ ei, int* __restrict__ cnt) {
  int e = blockIdx.x * blockDim.x + threadIdx.x;
  if (e < N_EDGES) atomicAdd(&cnt[ei[N_EDGES + e]], 1);
}

__global__ __launch_bounds__(1024) void k_scan(const int* __restrict__ cnt,
                                               int* __restrict__ row_ptr) {
  __shared__ int wsum[16];
  __shared__ int carryS;
  const int tid = threadIdx.x, lane = tid & 63, w = tid >> 6;
  if (tid == 0) carryS = 0;
  __syncthreads();
  for (int base = 0; base < N_NODES; base += 1024) {
    int idx = base + tid;
    int v = (idx < N_NODES) ? cnt[idx] : 0;
    int s = v;
    #pragma unroll
    for (int off = 1; off < 64; off <<= 1) {
      int t = __shfl_up(s, off);
      if (lane >= off) s += t;
    }
    if (lane == 63) wsum[w] = s;
    __syncthreads();
    if (w == 0 && lane < 16) {
      int ss = wsum[lane];
      #pragma unroll
      for (int off = 1; off < 16; off <<= 1) {
        int u = __shfl_up(ss, off);
        if (lane >= off) ss += u;
      }
      wsum[lane] = ss;   // inclusive wave-sum scan
    }
    __syncthreads();
    int waveoff = w ? wsum[w - 1] : 0;
    int carry = carryS;
    if (idx < N_NODES) row_ptr[idx] = carry + waveoff + s - v;  // exclusive
    __syncthreads();
    if (tid == 1023) carryS = carry + wsum[15];
    __syncthreads();
  }
  if (threadIdx.x == 0) row_ptr[N_NODES] = carryS;
}

__global__ void k_dinv(const int* __restrict__ cnt, float* __restrict__ dinv) {
  int n = blockIdx.x * blockDim.x + threadIdx.x;
  if (n < N_NODES) dinv[n] = rsqrtf((float)cnt[n] + 1.0f);  // +1 self-loop
}

__global__ void k_fill(const int* __restrict__ ei, const int* __restrict__ row_ptr,
                       int* __restrict__ fill, int* __restrict__ col) {
  int e = blockIdx.x * blockDim.x + threadIdx.x;
  if (e < N_EDGES) {
    int s = ei[e];
    int d = ei[N_EDGES + e];
    int pos = row_ptr[d] + atomicAdd(&fill[d], 1);
    col[pos] = s;
  }
}

// segment starts: starts[g] = lower_bound(batch, g); starts[NGRAPH] = N_NODES
__global__ void k_bounds(const int* __restrict__ batch, int* __restrict__ starts) {
  int g = blockIdx.x * blockDim.x + threadIdx.x;
  if (g > NGRAPH) return;
  if (g == NGRAPH) { starts[g] = N_NODES; return; }
  int lo = 0, hi = N_NODES;
  while (lo < hi) { int m = (lo + hi) >> 1; if (batch[m] < g) lo = m + 1; else hi = m; }
  starts[g] = lo;
}

// ============================ Weight transpose/convert ============================

// Wt[m][n][k] = W_m[k][n] as bf16; m = 0..2 -> Ws, m = 3 -> fc1_w
__global__ void k_cvtW(const float* __restrict__ Ws, const float* __restrict__ fc1_w,
                       unsigned short* __restrict__ Wt) {
  int idx = blockIdx.x * 256 + threadIdx.x;   // < 4*256*256
  int m = idx >> 16;
  int r = idx & 65535;
  int n = r >> 8;
  int k = r & 255;
  const float* src = (m < 3) ? (Ws + (size_t)m * 65536) : fc1_w;
  Wt[idx] = f2bf(src[k * 256 + n]);
}

// Wt2[n][k] = fc2_w[k][n] as bf16 (32x256)
__global__ void k_cvtW2(const float* __restrict__ fc2_w, unsigned short* __restrict__ Wt2) {
  int idx = blockIdx.x * 256 + threadIdx.x;   // < 32*256
  int n = idx >> 8;
  int k = idx & 255;
  Wt2[idx] = f2bf(fc2_w[k * 32 + n]);
}

// ============================ Aggregation ============================

// p0 = Ahat * x   (9 features, f32, thread per node)
__global__ void k_agg9(const float* __restrict__ x, const int* __restrict__ row_ptr,
                       const int* __restrict__ col, const float* __restrict__ dinv,
                       float* __restrict__ p0) {
  int n = blockIdx.x * blockDim.x + threadIdx.x;
  if (n >= N_NODES) return;
  float dn = dinv[n];
  float acc[IN_FEAT];
  float selfw = dn * dn;
  #pragma unroll
  for (int j = 0; j < IN_FEAT; ++j) acc[j] = x[n * IN_FEAT + j] * selfw;
  int beg = row_ptr[n], end = row_ptr[n + 1];
  for (int e = beg; e < end; ++e) {
    int s = col[e];
    float wgt = dinv[s] * dn;
    #pragma unroll
    for (int j = 0; j < IN_FEAT; ++j) acc[j] += x[s * IN_FEAT + j] * wgt;
  }
  #pragma unroll
  for (int j = 0; j < IN_FEAT; ++j) p0[n * IN_FEAT + j] = acc[j];
}

// p = Ahat * h   (256 bf16 features, one wave per node, 4 feats/lane, f32 acc)
__global__ __launch_bounds__(256) void k_agg256(
    const unsigned short* __restrict__ h, const int* __restrict__ row_ptr,
    const int* __restrict__ col, const float* __restrict__ dinv,
    unsigned short* __restrict__ p) {
  int wid = threadIdx.x >> 6;
  int lane = threadIdx.x & 63;
  int n = blockIdx.x * 4 + wid;
  if (n >= N_NODES) return;
  float dn = dinv[n];
  uint2 q = *(const uint2*)(h + (size_t)n * UNITS + lane * 4);
  float selfw = dn * dn;
  float a0 = bflo(q.x) * selfw, a1 = bfhi(q.x) * selfw;
  float a2 = bflo(q.y) * selfw, a3 = bfhi(q.y) * selfw;
  int e = row_ptr[n], end = row_ptr[n + 1];
  for (; e + 4 <= end; e += 4) {          // 4-edge unroll: 4 gathers in flight
    int s0 = col[e], s1 = col[e + 1], s2 = col[e + 2], s3 = col[e + 3];
    float w0 = dinv[s0] * dn, w1 = dinv[s1] * dn;
    float w2 = dinv[s2] * dn, w3 = dinv[s3] * dn;
    uint2 q0 = *(const uint2*)(h + (size_t)s0 * UNITS + lane * 4);
    uint2 q1 = *(const uint2*)(h + (size_t)s1 * UNITS + lane * 4);
    uint2 q2 = *(const uint2*)(h + (size_t)s2 * UNITS + lane * 4);
    uint2 q3 = *(const uint2*)(h + (size_t)s3 * UNITS + lane * 4);
    a0 += bflo(q0.x) * w0; a1 += bfhi(q0.x) * w0;
    a2 += bflo(q0.y) * w0; a3 += bfhi(q0.y) * w0;
    a0 += bflo(q1.x) * w1; a1 += bfhi(q1.x) * w1;
    a2 += bflo(q1.y) * w1; a3 += bfhi(q1.y) * w1;
    a0 += bflo(q2.x) * w2; a1 += bfhi(q2.x) * w2;
    a2 += bflo(q2.y) * w2; a3 += bfhi(q2.y) * w2;
    a0 += bflo(q3.x) * w3; a1 += bfhi(q3.x) * w3;
    a2 += bflo(q3.y) * w3; a3 += bfhi(q3.y) * w3;
  }
  for (; e < end; ++e) {
    int s0 = col[e];
    float w0 = dinv[s0] * dn;
    uint2 q0 = *(const uint2*)(h + (size_t)s0 * UNITS + lane * 4);
    a0 += bflo(q0.x) * w0; a1 += bfhi(q0.x) * w0;
    a2 += bflo(q0.y) * w0; a3 += bfhi(q0.y) * w0;
  }
  uint2 o;
  o.x = (unsigned int)f2bf(a0) | ((unsigned int)f2bf(a1) << 16);
  o.y = (unsigned int)f2bf(a2) | ((unsigned int)f2bf(a3) << 16);
  *(uint2*)(p + (size_t)n * UNITS + lane * 4) = o;
}

// ============================ GEMMs ============================

// h = tanh(p0 @ Win + bin) -> bf16   [N,9] x [9,256]
__global__ __launch_bounds__(256) void k_gemm9(const float* __restrict__ p0,
                                               const float* __restrict__ Win,
                                               const float* __restrict__ bin,
                                               unsigned short* __restrict__ h) {
  __shared__ float pS[32][IN_FEAT];
  int tid = threadIdx.x;
  int row0 = blockIdx.x * 32;
  for (int i = tid; i < 32 * IN_FEAT; i += 256) {
    int r = i / IN_FEAT;
    pS[r][i % IN_FEAT] = (row0 + r < N_NODES) ? p0[(size_t)row0 * IN_FEAT + i] : 0.0f;
  }
  float wcol[IN_FEAT];
  #pragma unroll
  for (int k = 0; k < IN_FEAT; ++k) wcol[k] = Win[k * UNITS + tid];
  float b = bin[tid];
  __syncthreads();
  for (int r = 0; r < 32; ++r) {
    int gr = row0 + r;
    if (gr >= N_NODES) break;
    float a = b;
    #pragma unroll
    for (int k = 0; k < IN_FEAT; ++k) a += pS[r][k] * wcol[k];
    h[(size_t)gr * UNITS + tid] = f2bf(tanhf(a));
  }
}

// C = tanh(A @ W + bias) in bf16. A:[M][256] bf16, Wt:[256][256] bf16 (Wt[n][k]).
// 4 waves/block; wave w owns rows [row0+16w, +16) x all 256 cols.
__global__ __launch_bounds__(256) void k_gemm_bf16(
    const unsigned short* __restrict__ A,
    const unsigned short* __restrict__ Wt,
    const float* __restrict__ bias,
    unsigned short* __restrict__ C,
    int M) {
  __shared__ unsigned short tS[64][264];   // 33.8 KiB, rows 528B (16B-aligned)
  const int tid = threadIdx.x;
  const int w = tid >> 6;
  const int l = tid & 63;
  const int l15 = l & 15;
  const int blk = l >> 4;
  const int row0 = blockIdx.x * 64;

  int r = row0 + 16 * w + l15;
  int rc = r < M ? r : M - 1;              // clamp loads; stores guarded below
  const unsigned short* aPtr = A + (size_t)rc * UNITS + 8 * blk;
  const unsigned short* bPtr = Wt + (size_t)l15 * UNITS + 8 * blk;

  f32x4 acc[16];
  #pragma unroll
  for (int cf = 0; cf < 16; ++cf) acc[cf] = (f32x4){0.f, 0.f, 0.f, 0.f};

  for (int k0 = 0; k0 < UNITS; k0 += 32) {
    bf16x8 a = *(const bf16x8*)(aPtr + k0);
    const unsigned short* bp = bPtr + k0;
    #pragma unroll
    for (int cf = 0; cf < 16; ++cf) {
      bf16x8 b = *(const bf16x8*)bp;
      acc[cf] = __builtin_amdgcn_mfma_f32_16x16x32_bf16(a, b, acc[cf], 0, 0, 0);
      bp += 16 * UNITS;
    }
  }

  // bias + tanh -> bf16 into LDS (C/D frag: col=lane&15, row=4*(lane>>4)+reg)
  #pragma unroll
  for (int cf = 0; cf < 16; ++cf) {
    float bcol = bias[cf * 16 + l15];
    #pragma unroll
    for (int reg = 0; reg < 4; ++reg) {
      float v = tanhf(acc[cf][reg] + bcol);
      tS[16 * w + 4 * blk + reg][cf * 16 + l15] = f2bf(v);
    }
  }
  __syncthreads();
  #pragma unroll
  for (int i = 0; i < 4; ++i) {            // coalesced 16B stores
    int flat8 = tid + i * 256;             // ushort8 index in 64x256 tile
    int rr = flat8 >> 5;
    int c8 = flat8 & 31;
    int gr = row0 + rr;
    if (gr < M) {
      uint4 v = *(const uint4*)&tS[rr][c8 * 8];
      *(uint4*)(C + (size_t)gr * UNITS + c8 * 8) = v;
    }
  }
}

// ============================ fused fc2 + tanh + fc3 (MFMA) -> node scalar ============================

// H:[M][256] bf16, Wt2:[32][256] bf16. Per wave: 16 rows x 32 cols (2 frags).
// Epilogue: tanh(acc+b2)*w3, shfl row-reduce over 16-lane col group,
// plain store of per-node scalar (no atomics).
__global__ __launch_bounds__(256) void k_fc23(
    const unsigned short* __restrict__ H,
    const unsigned short* __restrict__ Wt2,
    const float* __restrict__ b2,
    const float* __restrict__ w3, const float* __restrict__ b3,
    float* __restrict__ ns, int M) {
  const int tid = threadIdx.x;
  const int w = tid >> 6;
  const int l = tid & 63;
  const int l15 = l & 15;
  const int blk = l >> 4;
  const int row0 = blockIdx.x * 64 + 16 * w;

  int r = row0 + l15;
  int rc = r < M ? r : M - 1;
  const unsigned short* aPtr = H + (size_t)rc * UNITS + 8 * blk;
  const unsigned short* bPtr = Wt2 + (size_t)l15 * UNITS + 8 * blk;

  f32x4 acc0 = (f32x4){0.f, 0.f, 0.f, 0.f};
  f32x4 acc1 = (f32x4){0.f, 0.f, 0.f, 0.f};
  #pragma unroll
  for (int k0 = 0; k0 < UNITS; k0 += 32) {
    bf16x8 a  = *(const bf16x8*)(aPtr + k0);
    bf16x8 b0 = *(const bf16x8*)(bPtr + k0);
    bf16x8 b1 = *(const bf16x8*)(bPtr + 16 * UNITS + k0);
    acc0 = __builtin_amdgcn_mfma_f32_16x16x32_bf16(a, b0, acc0, 0, 0, 0);
    acc1 = __builtin_amdgcn_mfma_f32_16x16x32_bf16(a, b1, acc1, 0, 0, 0);
  }

  float c0 = b2[l15], c1 = b2[16 + l15];
  float w30 = w3[l15], w31 = w3[16 + l15];
  float b3v = b3[0];
  #pragma unroll
  for (int reg = 0; reg < 4; ++reg) {
    float part = tanhf(acc0[reg] + c0) * w30 + tanhf(acc1[reg] + c1) * w31;
    #pragma unroll
    for (int m = 8; m >= 1; m >>= 1) part += __shfl_xor(part, m);
    int gr = row0 + 4 * blk + reg;
    if (l15 == 0 && gr < M) ns[gr] = part + b3v;
  }
}

// one wave per graph: deterministic segment mean + sigmoid
__global__ __launch_bounds__(64) void k_pool(const float* __restrict__ ns,
                                             const int* __restrict__ starts,
                                             float* __restrict__ out) {
  int g = blockIdx.x;
  int lane = threadIdx.x;
  int s = starts[g], e = starts[g + 1];
  float acc = 0.0f;
  for (int i = s + lane; i < e; i += 64) acc += ns[i];
  #pragma unroll
  for (int m = 32; m >= 1; m >>= 1) acc += __shfl_xor(acc, m);
  if (lane == 0) {
    float mean = acc / fmaxf((float)(e - s), 1.0f);
    out[g] = 1.0f / (1.0f + expf(-mean));
  }
}

// ============================ launch ============================

extern "C" void kernel_launch(void* const* d_in, const int* in_sizes, int n_in,
                              void* d_out, int out_size, void* d_ws, size_t ws_size,
                              hipStream_t stream) {
  const float* x     = (const float*)d_in[0];
  const int*   ei    = (const int*)d_in[1];
  const int*   batch = (const int*)d_in[2];
  const float* Win   = (const float*)d_in[3];
  const float* bin_  = (const float*)d_in[4];
  const float* Ws    = (const float*)d_in[5];
  const float* bs    = (const float*)d_in[6];
  const float* fc1_w = (const float*)d_in[7];
  const float* fc1_b = (const float*)d_in[8];
  const float* fc2_w = (const float*)d_in[9];
  const float* fc2_b = (const float*)d_in[10];
  const float* fc3_w = (const float*)d_in[11];
  const float* fc3_b = (const float*)d_in[12];
  float* out = (float*)d_out;

  char* ws = (char*)d_ws;
  size_t off = 0;
  auto alloc = [&](size_t bytes) {
    size_t o = off;
    off = (off + bytes + 255) & ~(size_t)255;
    return o;
  };
  int*   cnt     = (int*)(ws + alloc(N_NODES * 4));
  int*   fill    = (int*)(ws + alloc(N_NODES * 4));
  int*   row_ptr = (int*)(ws + alloc((N_NODES + 1) * 4));
  float* dinv    = (float*)(ws + alloc(N_NODES * 4));
  int*   col     = (int*)(ws + alloc((size_t)N_EDGES * 4));
  int*   starts  = (int*)(ws + alloc((NGRAPH + 1) * 4));
  float* ns      = (float*)(ws + alloc(N_NODES * 4));
  float* p0      = (float*)(ws + alloc((size_t)N_NODES * IN_FEAT * 4));
  unsigned short* Wt   = (unsigned short*)(ws + alloc((size_t)4 * UNITS * UNITS * 2));
  unsigned short* Wt2  = (unsigned short*)(ws + alloc((size_t)32 * UNITS * 2));
  unsigned short* bufA = (unsigned short*)(ws + alloc((size_t)N_NODES * UNITS * 2));
  unsigned short* bufB = (unsigned short*)(ws + alloc((size_t)N_NODES * UNITS * 2));

  hipMemsetAsync(cnt, 0, N_NODES * 4, stream);
  hipMemsetAsync(fill, 0, N_NODES * 4, stream);

  // weights -> bf16 transposed
  k_cvtW<<<(4 * UNITS * UNITS) / 256, 256, 0, stream>>>(Ws, fc1_w, Wt);
  k_cvtW2<<<32, 256, 0, stream>>>(fc2_w, Wt2);

  // CSR build + per-graph segment bounds
  k_count<<<(N_EDGES + 255) / 256, 256, 0, stream>>>(ei, cnt);
  k_scan<<<1, 1024, 0, stream>>>(cnt, row_ptr);
  k_dinv<<<(N_NODES + 255) / 256, 256, 0, stream>>>(cnt, dinv);
  k_fill<<<(N_EDGES + 255) / 256, 256, 0, stream>>>(ei, row_ptr, fill, col);
  k_bounds<<<3, 256, 0, stream>>>(batch, starts);

  // layer 0: aggregate 9 f32 feats, GEMM 9->256 + tanh -> bf16
  k_agg9<<<(N_NODES + 255) / 256, 256, 0, stream>>>(x, row_ptr, col, dinv, p0);
  k_gemm9<<<(N_NODES + 31) / 32, 256, 0, stream>>>(p0, Win, bin_, bufA);

  // layers 1..3: bf16 aggregate, MFMA GEMM + tanh
  int ggrid = (N_NODES + 63) / 64;
  for (int i = 0; i < 3; ++i) {
    k_agg256<<<(N_NODES + 3) / 4, 256, 0, stream>>>(bufA, row_ptr, col, dinv, bufB);
    k_gemm_bf16<<<ggrid, 256, 0, stream>>>(bufB, Wt + (size_t)i * UNITS * UNITS,
                                           bs + (size_t)i * UNITS, bufA, N_NODES);
  }

  // fc1 + tanh
  k_gemm_bf16<<<ggrid, 256, 0, stream>>>(bufA, Wt + (size_t)3 * UNITS * UNITS,
                                         fc1_b, bufB, N_NODES);

  // fused fc2 + tanh + fc3 -> per-node scalar (no atomics)
  k_fc23<<<ggrid, 256, 0, stream>>>(bufB, Wt2, fc2_b, fc3_w, fc3_b, ns, N_NODES);

  // segment mean + sigmoid
  k_pool<<<NGRAPH, 64, 0, stream>>>(ns, starts, out);
}

// Round 5
// 976.369 us; speedup vs baseline: 2.1491x; 1.2436x over previous
//
#include <hip/hip_runtime.h>
#include <math.h>

#define N_NODES 100000
#define N_EDGES 1600000
#define UNITS   256
#define NGRAPH  512
#define IN_FEAT 9

typedef short bf16x8 __attribute__((ext_vector_type(8)));
typedef float f32x4  __attribute__((ext_vector_type(4)));

__device__ __forceinline__ float bflo(unsigned int u) {
  return __builtin_bit_cast(float, u << 16);
}
__device__ __forceinline__ float bfhi(unsigned int u) {
  return __builtin_bit_cast(float, u & 0xffff0000u);
}
__device__ __forceinline__ unsigned short f2bf(float f) {
  unsigned int u = __builtin_bit_cast(unsigned int, f);
  u += 0x7fffu + ((u >> 16) & 1u);   // round-to-nearest-even
  return (unsigned short)(u >> 16);
}

// byte offset into a [rows][64] bf16 LDS tile (128 B rows) with T2 XOR swizzle
__device__ __forceinline__ int swz(int row, int byteInRow) {
  return row * 128 + (byteInRow ^ ((row & 7) << 4));
}

// ============================ CSR build ============================

__global__ void k_count(const int* __restrict__ ei, int* __restrict__ cnt) {
  int e = blockIdx.x * blockDim.x + threadIdx.x;
  if (e < N_EDGES) atomicAdd(&cnt[ei[N_EDGES + e]], 1);
}

__global__ __launch_bounds__(1024) void k_scan(const int* __restrict__ cnt,
                                               int* __restrict__ row_ptr) {
  __shared__ int wsum[16];
  __shared__ int carryS;
  const int tid = threadIdx.x, lane = tid & 63, w = tid >> 6;
  if (tid == 0) carryS = 0;
  __syncthreads();
  for (int base = 0; base < N_NODES; base += 1024) {
    int idx = base + tid;
    int v = (idx < N_NODES) ? cnt[idx] : 0;
    int s = v;
    #pragma unroll
    for (int off = 1; off < 64; off <<= 1) {
      int t = __shfl_up(s, off);
      if (lane >= off) s += t;
    }
    if (lane == 63) wsum[w] = s;
    __syncthreads();
    if (w == 0 && lane < 16) {
      int ss = wsum[lane];
      #pragma unroll
      for (int off = 1; off < 16; off <<= 1) {
        int u = __shfl_up(ss, off);
        if (lane >= off) ss += u;
      }
      wsum[lane] = ss;   // inclusive wave-sum scan
    }
    __syncthreads();
    int waveoff = w ? wsum[w - 1] : 0;
    int carry = carryS;
    if (idx < N_NODES) row_ptr[idx] = carry + waveoff + s - v;  // exclusive
    __syncthreads();
    if (tid == 1023) carryS = carry + wsum[15];
    __syncthreads();
  }
  if (threadIdx.x == 0) row_ptr[N_NODES] = carryS;
}

__global__ void k_dinv(const int* __restrict__ cnt, float* __restrict__ dinv) {
  int n = blockIdx.x * blockDim.x + threadIdx.x;
  if (n < N_NODES) dinv[n] = rsqrtf((float)cnt[n] + 1.0f);  // +1 self-loop
}

__global__ void k_fill(const int* __restrict__ ei, const int* __restrict__ row_ptr,
                       int* __restrict__ fill, int* __restrict__ col) {
  int e = blockIdx.x * blockDim.x + threadIdx.x;
  if (e < N_EDGES) {
    int s = ei[e];
    int d = ei[N_EDGES + e];
    int pos = row_ptr[d] + atomicAdd(&fill[d], 1);
    col[pos] = s;
  }
}

// segment starts: starts[g] = lower_bound(batch, g); starts[NGRAPH] = N_NODES
__global__ void k_bounds(const int* __restrict__ batch, int* __restrict__ starts) {
  int g = blockIdx.x * blockDim.x + threadIdx.x;
  if (g > NGRAPH) return;
  if (g == NGRAPH) { starts[g] = N_NODES; return; }
  int lo = 0, hi = N_NODES;
  while (lo < hi) { int m = (lo + hi) >> 1; if (batch[m] < g) lo = m + 1; else hi = m; }
  starts[g] = lo;
}

// ============================ Weight transpose/convert ============================

// Wt[m][n][k] = W_m[k][n] as bf16; m = 0..2 -> Ws, m = 3 -> fc1_w
__global__ void k_cvtW(const float* __restrict__ Ws, const float* __restrict__ fc1_w,
                       unsigned short* __restrict__ Wt) {
  int idx = blockIdx.x * 256 + threadIdx.x;   // < 4*256*256
  int m = idx >> 16;
  int r = idx & 65535;
  int n = r >> 8;
  int k = r & 255;
  const float* src = (m < 3) ? (Ws + (size_t)m * 65536) : fc1_w;
  Wt[idx] = f2bf(src[k * 256 + n]);
}

// Wt2[n][k] = fc2_w[k][n] as bf16 (32x256)
__global__ void k_cvtW2(const float* __restrict__ fc2_w, unsigned short* __restrict__ Wt2) {
  int idx = blockIdx.x * 256 + threadIdx.x;   // < 32*256
  int n = idx >> 8;
  int k = idx & 255;
  Wt2[idx] = f2bf(fc2_w[k * 32 + n]);
}

// ============================ Aggregation ============================

// p0 = Ahat * x   (9 features, f32, thread per node)
__global__ void k_agg9(const float* __restrict__ x, const int* __restrict__ row_ptr,
                       const int* __restrict__ col, const float* __restrict__ dinv,
                       float* __restrict__ p0) {
  int n = blockIdx.x * blockDim.x + threadIdx.x;
  if (n >= N_NODES) return;
  float dn = dinv[n];
  float acc[IN_FEAT];
  float selfw = dn * dn;
  #pragma unroll
  for (int j = 0; j < IN_FEAT; ++j) acc[j] = x[n * IN_FEAT + j] * selfw;
  int beg = row_ptr[n], end = row_ptr[n + 1];
  for (int e = beg; e < end; ++e) {
    int s = col[e];
    float wgt = dinv[s] * dn;
    #pragma unroll
    for (int j = 0; j < IN_FEAT; ++j) acc[j] += x[s * IN_FEAT + j] * wgt;
  }
  #pragma unroll
  for (int j = 0; j < IN_FEAT; ++j) p0[n * IN_FEAT + j] = acc[j];
}

// p = Ahat * h   (256 bf16 features, one wave per node, 4 feats/lane, f32 acc)
__global__ __launch_bounds__(256) void k_agg256(
    const unsigned short* __restrict__ h, const int* __restrict__ row_ptr,
    const int* __restrict__ col, const float* __restrict__ dinv,
    unsigned short* __restrict__ p) {
  int wid = threadIdx.x >> 6;
  int lane = threadIdx.x & 63;
  int n = blockIdx.x * 4 + wid;
  if (n >= N_NODES) return;
  float dn = dinv[n];
  uint2 q = *(const uint2*)(h + (size_t)n * UNITS + lane * 4);
  float selfw = dn * dn;
  float a0 = bflo(q.x) * selfw, a1 = bfhi(q.x) * selfw;
  float a2 = bflo(q.y) * selfw, a3 = bfhi(q.y) * selfw;
  int e = row_ptr[n], end = row_ptr[n + 1];
  for (; e + 4 <= end; e += 4) {          // 4-edge unroll: 4 gathers in flight
    int s0 = col[e], s1 = col[e + 1], s2 = col[e + 2], s3 = col[e + 3];
    float w0 = dinv[s0] * dn, w1 = dinv[s1] * dn;
    float w2 = dinv[s2] * dn, w3 = dinv[s3] * dn;
    uint2 q0 = *(const uint2*)(h + (size_t)s0 * UNITS + lane * 4);
    uint2 q1 = *(const uint2*)(h + (size_t)s1 * UNITS + lane * 4);
    uint2 q2 = *(const uint2*)(h + (size_t)s2 * UNITS + lane * 4);
    uint2 q3 = *(const uint2*)(h + (size_t)s3 * UNITS + lane * 4);
    a0 += bflo(q0.x) * w0; a1 += bfhi(q0.x) * w0;
    a2 += bflo(q0.y) * w0; a3 += bfhi(q0.y) * w0;
    a0 += bflo(q1.x) * w1; a1 += bfhi(q1.x) * w1;
    a2 += bflo(q1.y) * w1; a3 += bfhi(q1.y) * w1;
    a0 += bflo(q2.x) * w2; a1 += bfhi(q2.x) * w2;
    a2 += bflo(q2.y) * w2; a3 += bfhi(q2.y) * w2;
    a0 += bflo(q3.x) * w3; a1 += bfhi(q3.x) * w3;
    a2 += bflo(q3.y) * w3; a3 += bfhi(q3.y) * w3;
  }
  for (; e < end; ++e) {
    int s0 = col[e];
    float w0 = dinv[s0] * dn;
    uint2 q0 = *(const uint2*)(h + (size_t)s0 * UNITS + lane * 4);
    a0 += bflo(q0.x) * w0; a1 += bfhi(q0.x) * w0;
    a2 += bflo(q0.y) * w0; a3 += bfhi(q0.y) * w0;
  }
  uint2 o;
  o.x = (unsigned int)f2bf(a0) | ((unsigned int)f2bf(a1) << 16);
  o.y = (unsigned int)f2bf(a2) | ((unsigned int)f2bf(a3) << 16);
  *(uint2*)(p + (size_t)n * UNITS + lane * 4) = o;
}

// ============================ GEMMs ============================

// h = tanh(p0 @ Win + bin) -> bf16   [N,9] x [9,256]
__global__ __launch_bounds__(256) void k_gemm9(const float* __restrict__ p0,
                                               const float* __restrict__ Win,
                                               const float* __restrict__ bin,
                                               unsigned short* __restrict__ h) {
  __shared__ float pS[32][IN_FEAT];
  int tid = threadIdx.x;
  int row0 = blockIdx.x * 32;
  for (int i = tid; i < 32 * IN_FEAT; i += 256) {
    int r = i / IN_FEAT;
    pS[r][i % IN_FEAT] = (row0 + r < N_NODES) ? p0[(size_t)row0 * IN_FEAT + i] : 0.0f;
  }
  float wcol[IN_FEAT];
  #pragma unroll
  for (int k = 0; k < IN_FEAT; ++k) wcol[k] = Win[k * UNITS + tid];
  float b = bin[tid];
  __syncthreads();
  for (int r = 0; r < 32; ++r) {
    int gr = row0 + r;
    if (gr >= N_NODES) break;
    float a = b;
    #pragma unroll
    for (int k = 0; k < IN_FEAT; ++k) a += pS[r][k] * wcol[k];
    h[(size_t)gr * UNITS + tid] = f2bf(tanhf(a));
  }
}

// C = tanh(A @ W + bias) in bf16. A:[M][256] bf16, Wt:[256][256] bf16 (Wt[n][k]).
// LDS-tiled: M=128 x N=256 block, K in 4 slices of 64.
// 4 waves in 2x2: wave(wr,wc) owns rows 64*wr..+63 x cols 128*wc..+127.
// A/B staged via registers into XOR-swizzled LDS ([*][64] bf16, 128B rows).
__global__ __launch_bounds__(256, 2) void k_gemm_bf16(
    const unsigned short* __restrict__ A,
    const unsigned short* __restrict__ Wt,
    const float* __restrict__ bias,
    unsigned short* __restrict__ C,
    int M) {
  __shared__ __align__(16) char lds[49152];   // 48 KiB
  char* As = lds;                  // [128][64] bf16 swizzled, 16 KiB
  char* Bs = lds + 16384;          // [256][64] bf16 swizzled, 32 KiB
  unsigned short (*Cs)[264] = (unsigned short(*)[264])lds;  // repack, 33.8 KiB (reused)

  const int tid = threadIdx.x;
  const int w = tid >> 6;
  const int l = tid & 63;
  const int l15 = l & 15;
  const int blk = l >> 4;
  const int wr = w >> 1;           // 0..1 row-group
  const int wc = w & 1;            // 0..1 col-group
  const int row0 = blockIdx.x * 128;

  const int sr = tid >> 3;         // 0..31 staging row base
  const int sc = (tid & 7) * 16;   // byte chunk in 128B row

  f32x4 acc[4][8];
  #pragma unroll
  for (int rf = 0; rf < 4; ++rf)
    #pragma unroll
    for (int cf = 0; cf < 8; ++cf) acc[rf][cf] = (f32x4){0.f, 0.f, 0.f, 0.f};

  for (int ks = 0; ks < 4; ++ks) {
    const int k0 = ks * 64;
    if (ks) __syncthreads();       // staging buffers free to overwrite
    // stage A slice [128][64]
    #pragma unroll
    for (int i = 0; i < 4; ++i) {
      int r = sr + i * 32;
      int gr = row0 + r; if (gr >= M) gr = M - 1;
      uint4 v = *(const uint4*)(A + (size_t)gr * UNITS + k0 + (sc >> 1));
      *(uint4*)(As + swz(r, sc)) = v;
    }
    // stage B slice [256][64]
    #pragma unroll
    for (int i = 0; i < 8; ++i) {
      int n = sr + i * 32;
      uint4 v = *(const uint4*)(Wt + (size_t)n * UNITS + k0 + (sc >> 1));
      *(uint4*)(Bs + swz(n, sc)) = v;
    }
    __syncthreads();
    #pragma unroll
    for (int kc = 0; kc < 2; ++kc) {
      const int kb = kc * 64 + blk * 16;   // byte offset of this lane's 16B k-chunk
      bf16x8 a[4];
      #pragma unroll
      for (int rf = 0; rf < 4; ++rf)
        a[rf] = *(const bf16x8*)(As + swz(64 * wr + rf * 16 + l15, kb));
      #pragma unroll
      for (int cf = 0; cf < 8; ++cf) {
        bf16x8 b = *(const bf16x8*)(Bs + swz(128 * wc + cf * 16 + l15, kb));
        #pragma unroll
        for (int rf = 0; rf < 4; ++rf)
          acc[rf][cf] = __builtin_amdgcn_mfma_f32_16x16x32_bf16(a[rf], b, acc[rf][cf], 0, 0, 0);
      }
    }
  }

  // epilogue: bias+tanh -> bf16, repack 64 rows at a time through LDS
  #pragma unroll
  for (int half = 0; half < 2; ++half) {
    __syncthreads();
    if (wr == half) {
      #pragma unroll
      for (int cf = 0; cf < 8; ++cf) {
        float bcol = bias[128 * wc + cf * 16 + l15];
        #pragma unroll
        for (int rf = 0; rf < 4; ++rf) {
          #pragma unroll
          for (int reg = 0; reg < 4; ++reg) {
            float v = tanhf(acc[rf][cf][reg] + bcol);
            Cs[rf * 16 + 4 * blk + reg][128 * wc + cf * 16 + l15] = f2bf(v);
          }
        }
      }
    }
    __syncthreads();
    #pragma unroll
    for (int j = 0; j < 8; ++j) {
      int flat = tid + j * 256;        // 0..2047 : 64 rows x 32 chunks
      int r = flat >> 5;
      int c = flat & 31;
      int gr = row0 + half * 64 + r;
      if (gr < M) {
        uint4 v = *(const uint4*)&Cs[r][c * 8];
        *(uint4*)(C + (size_t)gr * UNITS + c * 8) = v;
      }
    }
  }
}

// ============================ fused fc2 + tanh + fc3 (MFMA) -> node scalar ============================

__global__ __launch_bounds__(256) void k_fc23(
    const unsigned short* __restrict__ H,
    const unsigned short* __restrict__ Wt2,
    const float* __restrict__ b2,
    const float* __restrict__ w3, const float* __restrict__ b3,
    float* __restrict__ ns, int M) {
  const int tid = threadIdx.x;
  const int w = tid >> 6;
  const int l = tid & 63;
  const int l15 = l & 15;
  const int blk = l >> 4;
  const int row0 = blockIdx.x * 64 + 16 * w;

  int r = row0 + l15;
  int rc = r < M ? r : M - 1;
  const unsigned short* aPtr = H + (size_t)rc * UNITS + 8 * blk;
  const unsigned short* bPtr = Wt2 + (size_t)l15 * UNITS + 8 * blk;

  f32x4 acc0 = (f32x4){0.f, 0.f, 0.f, 0.f};
  f32x4 acc1 = (f32x4){0.f, 0.f, 0.f, 0.f};
  #pragma unroll
  for (int k0 = 0; k0 < UNITS; k0 += 32) {
    bf16x8 a  = *(const bf16x8*)(aPtr + k0);
    bf16x8 b0 = *(const bf16x8*)(bPtr + k0);
    bf16x8 b1 = *(const bf16x8*)(bPtr + 16 * UNITS + k0);
    acc0 = __builtin_amdgcn_mfma_f32_16x16x32_bf16(a, b0, acc0, 0, 0, 0);
    acc1 = __builtin_amdgcn_mfma_f32_16x16x32_bf16(a, b1, acc1, 0, 0, 0);
  }

  float c0 = b2[l15], c1 = b2[16 + l15];
  float w30 = w3[l15], w31 = w3[16 + l15];
  float b3v = b3[0];
  #pragma unroll
  for (int reg = 0; reg < 4; ++reg) {
    float part = tanhf(acc0[reg] + c0) * w30 + tanhf(acc1[reg] + c1) * w31;
    #pragma unroll
    for (int m = 8; m >= 1; m >>= 1) part += __shfl_xor(part, m);
    int gr = row0 + 4 * blk + reg;
    if (l15 == 0 && gr < M) ns[gr] = part + b3v;
  }
}

// one wave per graph: deterministic segment mean + sigmoid
__global__ __launch_bounds__(64) void k_pool(const float* __restrict__ ns,
                                             const int* __restrict__ starts,
                                             float* __restrict__ out) {
  int g = blockIdx.x;
  int lane = threadIdx.x;
  int s = starts[g], e = starts[g + 1];
  float acc = 0.0f;
  for (int i = s + lane; i < e; i += 64) acc += ns[i];
  #pragma unroll
  for (int m = 32; m >= 1; m >>= 1) acc += __shfl_xor(acc, m);
  if (lane == 0) {
    float mean = acc / fmaxf((float)(e - s), 1.0f);
    out[g] = 1.0f / (1.0f + expf(-mean));
  }
}

// ============================ launch ============================

extern "C" void kernel_launch(void* const* d_in, const int* in_sizes, int n_in,
                              void* d_out, int out_size, void* d_ws, size_t ws_size,
                              hipStream_t stream) {
  const float* x     = (const float*)d_in[0];
  const int*   ei    = (const int*)d_in[1];
  const int*   batch = (const int*)d_in[2];
  const float* Win   = (const float*)d_in[3];
  const float* bin_  = (const float*)d_in[4];
  const float* Ws    = (const float*)d_in[5];
  const float* bs    = (const float*)d_in[6];
  const float* fc1_w = (const float*)d_in[7];
  const float* fc1_b = (const float*)d_in[8];
  const float* fc2_w = (const float*)d_in[9];
  const float* fc2_b = (const float*)d_in[10];
  const float* fc3_w = (const float*)d_in[11];
  const float* fc3_b = (const float*)d_in[12];
  float* out = (float*)d_out;

  char* ws = (char*)d_ws;
  size_t off = 0;
  auto alloc = [&](size_t bytes) {
    size_t o = off;
    off = (off + bytes + 255) & ~(size_t)255;
    return o;
  };
  int*   cnt     = (int*)(ws + alloc(N_NODES * 4));
  int*   fill    = (int*)(ws + alloc(N_NODES * 4));
  int*   row_ptr = (int*)(ws + alloc((N_NODES + 1) * 4));
  float* dinv    = (float*)(ws + alloc(N_NODES * 4));
  int*   col     = (int*)(ws + alloc((size_t)N_EDGES * 4));
  int*   starts  = (int*)(ws + alloc((NGRAPH + 1) * 4));
  float* ns      = (float*)(ws + alloc(N_NODES * 4));
  float* p0      = (float*)(ws + alloc((size_t)N_NODES * IN_FEAT * 4));
  unsigned short* Wt   = (unsigned short*)(ws + alloc((size_t)4 * UNITS * UNITS * 2));
  unsigned short* Wt2  = (unsigned short*)(ws + alloc((size_t)32 * UNITS * 2));
  unsigned short* bufA = (unsigned short*)(ws + alloc((size_t)N_NODES * UNITS * 2));
  unsigned short* bufB = (unsigned short*)(ws + alloc((size_t)N_NODES * UNITS * 2));

  hipMemsetAsync(cnt, 0, N_NODES * 4, stream);
  hipMemsetAsync(fill, 0, N_NODES * 4, stream);

  // weights -> bf16 transposed
  k_cvtW<<<(4 * UNITS * UNITS) / 256, 256, 0, stream>>>(Ws, fc1_w, Wt);
  k_cvtW2<<<32, 256, 0, stream>>>(fc2_w, Wt2);

  // CSR build + per-graph segment bounds
  k_count<<<(N_EDGES + 255) / 256, 256, 0, stream>>>(ei, cnt);
  k_scan<<<1, 1024, 0, stream>>>(cnt, row_ptr);
  k_dinv<<<(N_NODES + 255) / 256, 256, 0, stream>>>(cnt, dinv);
  k_fill<<<(N_EDGES + 255) / 256, 256, 0, stream>>>(ei, row_ptr, fill, col);
  k_bounds<<<3, 256, 0, stream>>>(batch, starts);

  // layer 0: aggregate 9 f32 feats, GEMM 9->256 + tanh -> bf16
  k_agg9<<<(N_NODES + 255) / 256, 256, 0, stream>>>(x, row_ptr, col, dinv, p0);
  k_gemm9<<<(N_NODES + 31) / 32, 256, 0, stream>>>(p0, Win, bin_, bufA);

  // layers 1..3: bf16 aggregate, LDS-tiled MFMA GEMM + tanh
  int ggrid = (N_NODES + 127) / 128;
  for (int i = 0; i < 3; ++i) {
    k_agg256<<<(N_NODES + 3) / 4, 256, 0, stream>>>(bufA, row_ptr, col, dinv, bufB);
    k_gemm_bf16<<<ggrid, 256, 0, stream>>>(bufB, Wt + (size_t)i * UNITS * UNITS,
                                           bs + (size_t)i * UNITS, bufA, N_NODES);
  }

  // fc1 + tanh
  k_gemm_bf16<<<ggrid, 256, 0, stream>>>(bufA, Wt + (size_t)3 * UNITS * UNITS,
                                         fc1_b, bufB, N_NODES);

  // fused fc2 + tanh + fc3 -> per-node scalar (no atomics)
  k_fc23<<<(N_NODES + 63) / 64, 256, 0, stream>>>(bufB, Wt2, fc2_b, fc3_w, fc3_b, ns, N_NODES);

  // segment mean + sigmoid
  k_pool<<<NGRAPH, 64, 0, stream>>>(ns, starts, out);
}

// Round 6
// 862.312 us; speedup vs baseline: 2.4333x; 1.1323x over previous
//
#include <hip/hip_runtime.h>
#include <math.h>

#define N_NODES 100000
#define N_EDGES 1600000
#define UNITS   256
#define NGRAPH  512
#define IN_FEAT 9
#define NB_SCAN ((N_NODES + 255) / 256)   // 391

typedef short bf16x8 __attribute__((ext_vector_type(8)));
typedef float f32x4  __attribute__((ext_vector_type(4)));

__device__ __forceinline__ float bflo(unsigned int u) {
  return __builtin_bit_cast(float, u << 16);
}
__device__ __forceinline__ float bfhi(unsigned int u) {
  return __builtin_bit_cast(float, u & 0xffff0000u);
}
__device__ __forceinline__ unsigned short f2bf(float f) {
  unsigned int u = __builtin_bit_cast(unsigned int, f);
  u += 0x7fffu + ((u >> 16) & 1u);   // round-to-nearest-even
  return (unsigned short)(u >> 16);
}

// byte offset into a [rows][64] bf16 LDS tile (128 B rows) with T2 XOR swizzle
__device__ __forceinline__ int swz(int row, int byteInRow) {
  return row * 128 + (byteInRow ^ ((row & 7) << 4));
}

// ============================ CSR build ============================

__global__ void k_count(const int* __restrict__ ei, int* __restrict__ cnt) {
  int e = blockIdx.x * blockDim.x + threadIdx.x;
  if (e < N_EDGES) atomicAdd(&cnt[ei[N_EDGES + e]], 1);
}

// hierarchical scan: per-256-block sums
__global__ __launch_bounds__(256) void k_bsum(const int* __restrict__ cnt,
                                              int* __restrict__ bsum) {
  __shared__ int wsS[4];
  int b = blockIdx.x, tid = threadIdx.x, lane = tid & 63, w = tid >> 6;
  int idx = b * 256 + tid;
  int s = (idx < N_NODES) ? cnt[idx] : 0;
  #pragma unroll
  for (int m = 32; m >= 1; m >>= 1) s += __shfl_xor(s, m);
  if (lane == 0) wsS[w] = s;
  __syncthreads();
  if (tid == 0) bsum[b] = wsS[0] + wsS[1] + wsS[2] + wsS[3];
}

// exclusive scan of the NB_SCAN block sums (single 512-thread block)
__global__ __launch_bounds__(512) void k_bscan(int* __restrict__ bsum) {
  __shared__ int wsS[8];
  int tid = threadIdx.x, lane = tid & 63, w = tid >> 6;
  int v = (tid < NB_SCAN) ? bsum[tid] : 0;
  int s = v;
  #pragma unroll
  for (int off = 1; off < 64; off <<= 1) {
    int t = __shfl_up(s, off);
    if (lane >= off) s += t;
  }
  if (lane == 63) wsS[w] = s;
  __syncthreads();
  int woff = 0;
  #pragma unroll
  for (int i = 0; i < 8; ++i) woff += (i < w) ? wsS[i] : 0;
  if (tid < NB_SCAN) bsum[tid] = woff + s - v;   // exclusive
}

// block-local exclusive scan + global offset -> row_ptr
__global__ __launch_bounds__(256) void k_scan3(const int* __restrict__ cnt,
                                               const int* __restrict__ bsum,
                                               int* __restrict__ row_ptr) {
  __shared__ int wsS[4];
  int b = blockIdx.x, tid = threadIdx.x, lane = tid & 63, w = tid >> 6;
  int idx = b * 256 + tid;
  int v = (idx < N_NODES) ? cnt[idx] : 0;
  int s = v;
  #pragma unroll
  for (int off = 1; off < 64; off <<= 1) {
    int t = __shfl_up(s, off);
    if (lane >= off) s += t;
  }
  if (lane == 63) wsS[w] = s;
  __syncthreads();
  int woff = 0;
  #pragma unroll
  for (int i = 0; i < 4; ++i) woff += (i < w) ? wsS[i] : 0;
  if (idx < N_NODES) row_ptr[idx] = bsum[b] + woff + s - v;
  if (idx == 0) row_ptr[N_NODES] = N_EDGES;
}

__global__ void k_dinv(const int* __restrict__ cnt, float* __restrict__ dinv) {
  int n = blockIdx.x * blockDim.x + threadIdx.x;
  if (n < N_NODES) dinv[n] = rsqrtf((float)cnt[n] + 1.0f);  // +1 self-loop
}

__global__ void k_fill(const int* __restrict__ ei, const int* __restrict__ row_ptr,
                       int* __restrict__ fill, int* __restrict__ col) {
  int e = blockIdx.x * blockDim.x + threadIdx.x;
  if (e < N_EDGES) {
    int s = ei[e];
    int d = ei[N_EDGES + e];
    int pos = row_ptr[d] + atomicAdd(&fill[d], 1);
    col[pos] = s;
  }
}

// segment starts: starts[g] = lower_bound(batch, g); starts[NGRAPH] = N_NODES
__global__ void k_bounds(const int* __restrict__ batch, int* __restrict__ starts) {
  int g = blockIdx.x * blockDim.x + threadIdx.x;
  if (g > NGRAPH) return;
  if (g == NGRAPH) { starts[g] = N_NODES; return; }
  int lo = 0, hi = N_NODES;
  while (lo < hi) { int m = (lo + hi) >> 1; if (batch[m] < g) lo = m + 1; else hi = m; }
  starts[g] = lo;
}

// ============================ Weight transpose/convert ============================

// Wt[m][n][k] = W_m[k][n] as bf16; m = 0..2 -> Ws, m = 3 -> fc1_w
__global__ void k_cvtW(const float* __restrict__ Ws, const float* __restrict__ fc1_w,
                       unsigned short* __restrict__ Wt) {
  int idx = blockIdx.x * 256 + threadIdx.x;   // < 4*256*256
  int m = idx >> 16;
  int r = idx & 65535;
  int n = r >> 8;
  int k = r & 255;
  const float* src = (m < 3) ? (Ws + (size_t)m * 65536) : fc1_w;
  Wt[idx] = f2bf(src[k * 256 + n]);
}

// Wt2[n][k] = fc2_w[k][n] as bf16 (32x256)
__global__ void k_cvtW2(const float* __restrict__ fc2_w, unsigned short* __restrict__ Wt2) {
  int idx = blockIdx.x * 256 + threadIdx.x;   // < 32*256
  int n = idx >> 8;
  int k = idx & 255;
  Wt2[idx] = f2bf(fc2_w[k * 32 + n]);
}

// xs = dinv (x) x  (pre-scaled input features, f32)
__global__ void k_scalex(const float* __restrict__ x, const float* __restrict__ dinv,
                         float* __restrict__ xs) {
  int idx = blockIdx.x * blockDim.x + threadIdx.x;
  if (idx < N_NODES * IN_FEAT) xs[idx] = x[idx] * dinv[idx / IN_FEAT];
}

// ============================ Aggregation ============================

// p0 = dn * (xs[n] + sum xs[src])   (9 features, f32, thread per node)
__global__ void k_agg9(const float* __restrict__ xs, const int* __restrict__ row_ptr,
                       const int* __restrict__ col, const float* __restrict__ dinv,
                       float* __restrict__ p0) {
  int n = blockIdx.x * blockDim.x + threadIdx.x;
  if (n >= N_NODES) return;
  float acc[IN_FEAT];
  #pragma unroll
  for (int j = 0; j < IN_FEAT; ++j) acc[j] = xs[n * IN_FEAT + j];
  int beg = row_ptr[n], end = row_ptr[n + 1];
  for (int e = beg; e < end; ++e) {
    int s = col[e];
    #pragma unroll
    for (int j = 0; j < IN_FEAT; ++j) acc[j] += xs[s * IN_FEAT + j];
  }
  float dn = dinv[n];
  #pragma unroll
  for (int j = 0; j < IN_FEAT; ++j) p0[n * IN_FEAT + j] = dn * acc[j];
}

// p = dn * (hs[n] + sum hs[src])  (hs pre-scaled by dinv; pure gather+add)
// one wave per node, 4 feats/lane, f32 acc; 8/4/1-deep edge pipelining
__global__ __launch_bounds__(256) void k_agg256(
    const unsigned short* __restrict__ hs, const int* __restrict__ row_ptr,
    const int* __restrict__ col, const float* __restrict__ dinv,
    unsigned short* __restrict__ p) {
  int wid = threadIdx.x >> 6;
  int lane = threadIdx.x & 63;
  int n = blockIdx.x * 4 + wid;
  if (n >= N_NODES) return;
  uint2 q = *(const uint2*)(hs + (size_t)n * UNITS + lane * 4);
  float a0 = bflo(q.x), a1 = bfhi(q.x);
  float a2 = bflo(q.y), a3 = bfhi(q.y);
  int e = row_ptr[n], end = row_ptr[n + 1];
  for (; e + 8 <= end; e += 8) {          // 8 gathers in flight
    int s[8];
    uint2 qq[8];
    #pragma unroll
    for (int j = 0; j < 8; ++j) s[j] = col[e + j];
    #pragma unroll
    for (int j = 0; j < 8; ++j)
      qq[j] = *(const uint2*)(hs + (size_t)s[j] * UNITS + lane * 4);
    #pragma unroll
    for (int j = 0; j < 8; ++j) {
      a0 += bflo(qq[j].x); a1 += bfhi(qq[j].x);
      a2 += bflo(qq[j].y); a3 += bfhi(qq[j].y);
    }
  }
  if (e + 4 <= end) {
    int s[4];
    uint2 qq[4];
    #pragma unroll
    for (int j = 0; j < 4; ++j) s[j] = col[e + j];
    #pragma unroll
    for (int j = 0; j < 4; ++j)
      qq[j] = *(const uint2*)(hs + (size_t)s[j] * UNITS + lane * 4);
    #pragma unroll
    for (int j = 0; j < 4; ++j) {
      a0 += bflo(qq[j].x); a1 += bfhi(qq[j].x);
      a2 += bflo(qq[j].y); a3 += bfhi(qq[j].y);
    }
    e += 4;
  }
  for (; e < end; ++e) {
    int s0 = col[e];
    uint2 q0 = *(const uint2*)(hs + (size_t)s0 * UNITS + lane * 4);
    a0 += bflo(q0.x); a1 += bfhi(q0.x);
    a2 += bflo(q0.y); a3 += bfhi(q0.y);
  }
  float dn = dinv[n];
  uint2 o;
  o.x = (unsigned int)f2bf(dn * a0) | ((unsigned int)f2bf(dn * a1) << 16);
  o.y = (unsigned int)f2bf(dn * a2) | ((unsigned int)f2bf(dn * a3) << 16);
  *(uint2*)(p + (size_t)n * UNITS + lane * 4) = o;
}

// ============================ GEMMs ============================

// h = scale? * tanh(p0 @ Win + bin) -> bf16   [N,9] x [9,256]
__global__ __launch_bounds__(256) void k_gemm9(const float* __restrict__ p0,
                                               const float* __restrict__ Win,
                                               const float* __restrict__ bin,
                                               const float* __restrict__ scale,
                                               unsigned short* __restrict__ h) {
  __shared__ float pS[32][IN_FEAT];
  int tid = threadIdx.x;
  int row0 = blockIdx.x * 32;
  for (int i = tid; i < 32 * IN_FEAT; i += 256) {
    int r = i / IN_FEAT;
    pS[r][i % IN_FEAT] = (row0 + r < N_NODES) ? p0[(size_t)row0 * IN_FEAT + i] : 0.0f;
  }
  float wcol[IN_FEAT];
  #pragma unroll
  for (int k = 0; k < IN_FEAT; ++k) wcol[k] = Win[k * UNITS + tid];
  float b = bin[tid];
  __syncthreads();
  for (int r = 0; r < 32; ++r) {
    int gr = row0 + r;
    if (gr >= N_NODES) break;
    float a = b;
    #pragma unroll
    for (int k = 0; k < IN_FEAT; ++k) a += pS[r][k] * wcol[k];
    float sc = scale ? scale[gr] : 1.0f;
    h[(size_t)gr * UNITS + tid] = f2bf(sc * tanhf(a));
  }
}

// C = scale? * tanh(A @ W + bias) in bf16. A:[M][256], Wt:[256][256] (Wt[n][k]).
// LDS-tiled: M=128 x N=256 block, K in 4 slices of 64.
__global__ __launch_bounds__(256, 2) void k_gemm_bf16(
    const unsigned short* __restrict__ A,
    const unsigned short* __restrict__ Wt,
    const float* __restrict__ bias,
    const float* __restrict__ scale,   // nullable: per-row output scaling (dinv)
    unsigned short* __restrict__ C,
    int M) {
  __shared__ __align__(16) char lds[49152];   // 48 KiB
  char* As = lds;                  // [128][64] bf16 swizzled, 16 KiB
  char* Bs = lds + 16384;          // [256][64] bf16 swizzled, 32 KiB
  unsigned short (*Cs)[264] = (unsigned short(*)[264])lds;  // repack (reused)

  const int tid = threadIdx.x;
  const int w = tid >> 6;
  const int l = tid & 63;
  const int l15 = l & 15;
  const int blk = l >> 4;
  const int wr = w >> 1;           // 0..1 row-group
  const int wc = w & 1;            // 0..1 col-group
  const int row0 = blockIdx.x * 128;

  const int sr = tid >> 3;         // 0..31 staging row base
  const int sc = (tid & 7) * 16;   // byte chunk in 128B row

  f32x4 acc[4][8];
  #pragma unroll
  for (int rf = 0; rf < 4; ++rf)
    #pragma unroll
    for (int cf = 0; cf < 8; ++cf) acc[rf][cf] = (f32x4){0.f, 0.f, 0.f, 0.f};

  for (int ks = 0; ks < 4; ++ks) {
    const int k0 = ks * 64;
    if (ks) __syncthreads();
    #pragma unroll
    for (int i = 0; i < 4; ++i) {   // stage A slice [128][64]
      int r = sr + i * 32;
      int gr = row0 + r; if (gr >= M) gr = M - 1;
      uint4 v = *(const uint4*)(A + (size_t)gr * UNITS + k0 + (sc >> 1));
      *(uint4*)(As + swz(r, sc)) = v;
    }
    #pragma unroll
    for (int i = 0; i < 8; ++i) {   // stage B slice [256][64]
      int n = sr + i * 32;
      uint4 v = *(const uint4*)(Wt + (size_t)n * UNITS + k0 + (sc >> 1));
      *(uint4*)(Bs + swz(n, sc)) = v;
    }
    __syncthreads();
    #pragma unroll
    for (int kc = 0; kc < 2; ++kc) {
      const int kb = kc * 64 + blk * 16;
      bf16x8 a[4];
      #pragma unroll
      for (int rf = 0; rf < 4; ++rf)
        a[rf] = *(const bf16x8*)(As + swz(64 * wr + rf * 16 + l15, kb));
      #pragma unroll
      for (int cf = 0; cf < 8; ++cf) {
        bf16x8 b = *(const bf16x8*)(Bs + swz(128 * wc + cf * 16 + l15, kb));
        #pragma unroll
        for (int rf = 0; rf < 4; ++rf)
          acc[rf][cf] = __builtin_amdgcn_mfma_f32_16x16x32_bf16(a[rf], b, acc[rf][cf], 0, 0, 0);
      }
    }
  }

  // epilogue: bias+tanh (+optional dinv row-scale) -> bf16, repack via LDS
  #pragma unroll
  for (int half = 0; half < 2; ++half) {
    __syncthreads();
    if (wr == half) {
      float dvv[4][4];
      #pragma unroll
      for (int rf = 0; rf < 4; ++rf)
        #pragma unroll
        for (int reg = 0; reg < 4; ++reg) {
          int gr = row0 + 64 * half + rf * 16 + 4 * blk + reg;
          dvv[rf][reg] = scale ? scale[gr < M ? gr : M - 1] : 1.0f;
        }
      #pragma unroll
      for (int cf = 0; cf < 8; ++cf) {
        float bcol = bias[128 * wc + cf * 16 + l15];
        #pragma unroll
        for (int rf = 0; rf < 4; ++rf) {
          #pragma unroll
          for (int reg = 0; reg < 4; ++reg) {
            float v = dvv[rf][reg] * tanhf(acc[rf][cf][reg] + bcol);
            Cs[rf * 16 + 4 * blk + reg][128 * wc + cf * 16 + l15] = f2bf(v);
          }
        }
      }
    }
    __syncthreads();
    #pragma unroll
    for (int j = 0; j < 8; ++j) {
      int flat = tid + j * 256;        // 64 rows x 32 chunks
      int r = flat >> 5;
      int c = flat & 31;
      int gr = row0 + half * 64 + r;
      if (gr < M) {
        uint4 v = *(const uint4*)&Cs[r][c * 8];
        *(uint4*)(C + (size_t)gr * UNITS + c * 8) = v;
      }
    }
  }
}

// ============================ fused fc2 + tanh + fc3 (MFMA) -> node scalar ============================

__global__ __launch_bounds__(256) void k_fc23(
    const unsigned short* __restrict__ H,
    const unsigned short* __restrict__ Wt2,
    const float* __restrict__ b2,
    const float* __restrict__ w3, const float* __restrict__ b3,
    float* __restrict__ ns, int M) {
  const int tid = threadIdx.x;
  const int w = tid >> 6;
  const int l = tid & 63;
  const int l15 = l & 15;
  const int blk = l >> 4;
  const int row0 = blockIdx.x * 64 + 16 * w;

  int r = row0 + l15;
  int rc = r < M ? r : M - 1;
  const unsigned short* aPtr = H + (size_t)rc * UNITS + 8 * blk;
  const unsigned short* bPtr = Wt2 + (size_t)l15 * UNITS + 8 * blk;

  f32x4 acc0 = (f32x4){0.f, 0.f, 0.f, 0.f};
  f32x4 acc1 = (f32x4){0.f, 0.f, 0.f, 0.f};
  #pragma unroll
  for (int k0 = 0; k0 < UNITS; k0 += 32) {
    bf16x8 a  = *(const bf16x8*)(aPtr + k0);
    bf16x8 b0 = *(const bf16x8*)(bPtr + k0);
    bf16x8 b1 = *(const bf16x8*)(bPtr + 16 * UNITS + k0);
    acc0 = __builtin_amdgcn_mfma_f32_16x16x32_bf16(a, b0, acc0, 0, 0, 0);
    acc1 = __builtin_amdgcn_mfma_f32_16x16x32_bf16(a, b1, acc1, 0, 0, 0);
  }

  float c0 = b2[l15], c1 = b2[16 + l15];
  float w30 = w3[l15], w31 = w3[16 + l15];
  float b3v = b3[0];
  #pragma unroll
  for (int reg = 0; reg < 4; ++reg) {
    float part = tanhf(acc0[reg] + c0) * w30 + tanhf(acc1[reg] + c1) * w31;
    #pragma unroll
    for (int m = 8; m >= 1; m >>= 1) part += __shfl_xor(part, m);
    int gr = row0 + 4 * blk + reg;
    if (l15 == 0 && gr < M) ns[gr] = part + b3v;
  }
}

// one wave per graph: deterministic segment mean + sigmoid
__global__ __launch_bounds__(64) void k_pool(const float* __restrict__ ns,
                                             const int* __restrict__ starts,
                                             float* __restrict__ out) {
  int g = blockIdx.x;
  int lane = threadIdx.x;
  int s = starts[g], e = starts[g + 1];
  float acc = 0.0f;
  for (int i = s + lane; i < e; i += 64) acc += ns[i];
  #pragma unroll
  for (int m = 32; m >= 1; m >>= 1) acc += __shfl_xor(acc, m);
  if (lane == 0) {
    float mean = acc / fmaxf((float)(e - s), 1.0f);
    out[g] = 1.0f / (1.0f + expf(-mean));
  }
}

// ============================ launch ============================

extern "C" void kernel_launch(void* const* d_in, const int* in_sizes, int n_in,
                              void* d_out, int out_size, void* d_ws, size_t ws_size,
                              hipStream_t stream) {
  const float* x     = (const float*)d_in[0];
  const int*   ei    = (const int*)d_in[1];
  const int*   batch = (const int*)d_in[2];
  const float* Win   = (const float*)d_in[3];
  const float* bin_  = (const float*)d_in[4];
  const float* Ws    = (const float*)d_in[5];
  const float* bs    = (const float*)d_in[6];
  const float* fc1_w = (const float*)d_in[7];
  const float* fc1_b = (const float*)d_in[8];
  const float* fc2_w = (const float*)d_in[9];
  const float* fc2_b = (const float*)d_in[10];
  const float* fc3_w = (const float*)d_in[11];
  const float* fc3_b = (const float*)d_in[12];
  float* out = (float*)d_out;

  char* ws = (char*)d_ws;
  size_t off = 0;
  auto alloc = [&](size_t bytes) {
    size_t o = off;
    off = (off + bytes + 255) & ~(size_t)255;
    return o;
  };
  int*   cnt     = (int*)(ws + alloc(N_NODES * 4));
  int*   fill    = (int*)(ws + alloc(N_NODES * 4));
  int*   row_ptr = (int*)(ws + alloc((N_NODES + 1) * 4));
  float* dinv    = (float*)(ws + alloc(N_NODES * 4));
  int*   col     = (int*)(ws + alloc((size_t)N_EDGES * 4));
  int*   bsum    = (int*)(ws + alloc(NB_SCAN * 4));
  int*   starts  = (int*)(ws + alloc((NGRAPH + 1) * 4));
  float* ns      = (float*)(ws + alloc(N_NODES * 4));
  float* xs      = (float*)(ws + alloc((size_t)N_NODES * IN_FEAT * 4));
  float* p0      = (float*)(ws + alloc((size_t)N_NODES * IN_FEAT * 4));
  unsigned short* Wt   = (unsigned short*)(ws + alloc((size_t)4 * UNITS * UNITS * 2));
  unsigned short* Wt2  = (unsigned short*)(ws + alloc((size_t)32 * UNITS * 2));
  unsigned short* bufA = (unsigned short*)(ws + alloc((size_t)N_NODES * UNITS * 2));
  unsigned short* bufB = (unsigned short*)(ws + alloc((size_t)N_NODES * UNITS * 2));

  hipMemsetAsync(cnt, 0, N_NODES * 4, stream);
  hipMemsetAsync(fill, 0, N_NODES * 4, stream);

  // weights -> bf16 transposed
  k_cvtW<<<(4 * UNITS * UNITS) / 256, 256, 0, stream>>>(Ws, fc1_w, Wt);
  k_cvtW2<<<32, 256, 0, stream>>>(fc2_w, Wt2);

  // CSR build (hierarchical scan) + per-graph segment bounds
  k_count<<<(N_EDGES + 255) / 256, 256, 0, stream>>>(ei, cnt);
  k_bsum<<<NB_SCAN, 256, 0, stream>>>(cnt, bsum);
  k_bscan<<<1, 512, 0, stream>>>(bsum);
  k_scan3<<<NB_SCAN, 256, 0, stream>>>(cnt, bsum, row_ptr);
  k_dinv<<<(N_NODES + 255) / 256, 256, 0, stream>>>(cnt, dinv);
  k_fill<<<(N_EDGES + 255) / 256, 256, 0, stream>>>(ei, row_ptr, fill, col);
  k_bounds<<<3, 256, 0, stream>>>(batch, starts);

  // layer 0: pre-scale x, aggregate 9 f32 feats, GEMM 9->256 + tanh (scaled)
  k_scalex<<<(N_NODES * IN_FEAT + 255) / 256, 256, 0, stream>>>(x, dinv, xs);
  k_agg9<<<(N_NODES + 255) / 256, 256, 0, stream>>>(xs, row_ptr, col, dinv, p0);
  k_gemm9<<<(N_NODES + 31) / 32, 256, 0, stream>>>(p0, Win, bin_, dinv, bufA);

  // layers 1..3: pure-gather aggregate, LDS-tiled MFMA GEMM + tanh
  int ggrid = (N_NODES + 127) / 128;
  for (int i = 0; i < 3; ++i) {
    k_agg256<<<(N_NODES + 3) / 4, 256, 0, stream>>>(bufA, row_ptr, col, dinv, bufB);
    const float* sc = (i < 2) ? dinv : nullptr;   // last GCN layer feeds fc1 unscaled
    k_gemm_bf16<<<ggrid, 256, 0, stream>>>(bufB, Wt + (size_t)i * UNITS * UNITS,
                                           bs + (size_t)i * UNITS, sc, bufA, N_NODES);
  }

  // fc1 + tanh (unscaled)
  k_gemm_bf16<<<ggrid, 256, 0, stream>>>(bufA, Wt + (size_t)3 * UNITS * UNITS,
                                         fc1_b, nullptr, bufB, N_NODES);

  // fused fc2 + tanh + fc3 -> per-node scalar
  k_fc23<<<(N_NODES + 63) / 64, 256, 0, stream>>>(bufB, Wt2, fc2_b, fc3_w, fc3_b, ns, N_NODES);

  // segment mean + sigmoid
  k_pool<<<NGRAPH, 64, 0, stream>>>(ns, starts, out);
}